// Round 2
// baseline (530.212 us; speedup 1.0000x reference)
//
#include <hip/hip_runtime.h>
#include <hip/hip_bf16.h>
#include <math.h>

#define N_NODES 100000
#define N_EDGES 1600000

typedef unsigned int uint;
typedef unsigned short ushort_t;

__device__ __forceinline__ float bf2f(uint h) {
    union { uint u; float f; } x; x.u = h << 16; return x.f;
}
__device__ __forceinline__ unsigned short f2bf(float f) {
    union { float f; uint u; } x; x.f = f;
    uint u = x.u;
    return (unsigned short)((u + 0x7fffu + ((u >> 16) & 1u)) >> 16);  // RNE
}

// ---------------- edge dtype detection ----------------
// If edge_index is int64 (little-endian, values < 2^31), every odd int32 word
// of the first 1024 is a zero high-word. If int32 random data, some are nonzero.
__global__ void k_detect(const int* __restrict__ ei, int* __restrict__ flag) {
    int t = threadIdx.x;
    int v = ei[2 * t + 1] | ei[2 * (t + 256) + 1];
    if (v) atomicOr(flag, 1);  // 1 => int32 layout
}

__device__ __forceinline__ int edge_at(const int* __restrict__ ei, int is32, long long idx) {
    return is32 ? ei[idx] : (int)(((const long long*)ei)[idx]);
}

// ---------------- CSR build ----------------

__global__ void k_hist(const int* __restrict__ ei, const int* __restrict__ flag,
                       int* __restrict__ deg) {
    int e = blockIdx.x * blockDim.x + threadIdx.x;
    int is32 = *flag;
    if (e < N_EDGES) atomicAdd(&deg[edge_at(ei, is32, (long long)N_EDGES + e)], 1);
}

__global__ void k_dinv(const int* __restrict__ deg, float* __restrict__ dinv) {
    int i = blockIdx.x * blockDim.x + threadIdx.x;
    if (i < N_NODES) dinv[i] = rsqrtf((float)(deg[i] + 1));  // +1 self loop
}

__global__ void k_scan_local(const int* __restrict__ deg, int* __restrict__ row_start,
                             int* __restrict__ blk) {
    __shared__ int sums[256];
    int t = threadIdx.x;
    int base = blockIdx.x * 1024;
    int idx = base + t * 4;
    int v0 = 0, v1 = 0, v2 = 0, v3 = 0;
    if (idx + 3 < N_NODES) {
        int4 v = *(const int4*)(deg + idx);
        v0 = v.x; v1 = v.y; v2 = v.z; v3 = v.w;
    } else {
        if (idx + 0 < N_NODES) v0 = deg[idx + 0];
        if (idx + 1 < N_NODES) v1 = deg[idx + 1];
        if (idx + 2 < N_NODES) v2 = deg[idx + 2];
        if (idx + 3 < N_NODES) v3 = deg[idx + 3];
    }
    int tsum = v0 + v1 + v2 + v3;
    sums[t] = tsum;
    __syncthreads();
    int val = tsum;
    for (int off = 1; off < 256; off <<= 1) {
        int tmp = (t >= off) ? sums[t - off] : 0;
        __syncthreads();
        val += tmp;
        sums[t] = val;
        __syncthreads();
    }
    int excl = val - tsum;
    if (t == 255) blk[blockIdx.x] = val;
    if (idx + 0 < N_NODES) row_start[idx + 0] = excl;
    if (idx + 1 < N_NODES) row_start[idx + 1] = excl + v0;
    if (idx + 2 < N_NODES) row_start[idx + 2] = excl + v0 + v1;
    if (idx + 3 < N_NODES) row_start[idx + 3] = excl + v0 + v1 + v2;
}

__global__ void k_scan_blk(int* __restrict__ blk, int nb) {
    __shared__ int s[128];
    int t = threadIdx.x;
    int v = (t < nb) ? blk[t] : 0;
    s[t] = v;
    __syncthreads();
    int val = v;
    for (int off = 1; off < 128; off <<= 1) {
        int tmp = (t >= off) ? s[t - off] : 0;
        __syncthreads();
        val += tmp;
        s[t] = val;
        __syncthreads();
    }
    if (t < nb) blk[t] = val - v;  // exclusive
}

__global__ void k_scan_add(int* __restrict__ row_start, const int* __restrict__ blk) {
    int t = threadIdx.x;
    int base = blockIdx.x * 1024;
    int add = blk[blockIdx.x];
    int idx = base + t * 4;
    #pragma unroll
    for (int i = 0; i < 4; i++)
        if (idx + i < N_NODES) row_start[idx + i] += add;
    if (blockIdx.x == 0 && t == 0) row_start[N_NODES] = N_EDGES;
}

__global__ void k_fill(const int* __restrict__ ei, const int* __restrict__ flag,
                       const int* __restrict__ row_start, int* __restrict__ cursor,
                       int* __restrict__ csr_src) {
    int e = blockIdx.x * blockDim.x + threadIdx.x;
    int is32 = *flag;
    if (e < N_EDGES) {
        int d = edge_at(ei, is32, (long long)N_EDGES + e);
        int s = edge_at(ei, is32, e);
        int pos = row_start[d] + atomicAdd(&cursor[d], 1);
        csr_src[pos] = s;
    }
}

// ---------------- Layer compute ----------------

// g1 = bf16((x @ W1) * dinv[row]); x [N,128] f32, W1 [128,128] f32
__global__ __launch_bounds__(256) void k_gemm1(const float* __restrict__ x,
                                               const float* __restrict__ W,
                                               const float* __restrict__ dinv,
                                               ushort_t* __restrict__ g1) {
    __shared__ __align__(16) float Ws[32][128];
    __shared__ float Xs[64][33];
    int t = threadIdx.x;
    int row0 = blockIdx.x * 64;
    int c0 = (t & 31) * 4;
    int r0 = (t >> 5) * 8;
    float acc[8][4] = {};
    for (int k0 = 0; k0 < 128; k0 += 32) {
        #pragma unroll
        for (int i = 0; i < 16; i++) {
            int f = i * 256 + t;
            int kk = f >> 7, c = f & 127;
            Ws[kk][c] = W[(k0 + kk) * 128 + c];
        }
        #pragma unroll
        for (int i = 0; i < 8; i++) {
            int f = i * 256 + t;
            int r = f >> 5, kk = f & 31;
            int row = row0 + r;
            Xs[r][kk] = (row < N_NODES) ? x[row * 128 + k0 + kk] : 0.0f;
        }
        __syncthreads();
        #pragma unroll
        for (int kk = 0; kk < 32; kk++) {
            float4 b = *(const float4*)&Ws[kk][c0];
            #pragma unroll
            for (int i = 0; i < 8; i++) {
                float a = Xs[r0 + i][kk];
                acc[i][0] += a * b.x;
                acc[i][1] += a * b.y;
                acc[i][2] += a * b.z;
                acc[i][3] += a * b.w;
            }
        }
        __syncthreads();
    }
    #pragma unroll
    for (int i = 0; i < 8; i++) {
        int row = row0 + r0 + i;
        if (row < N_NODES) {
            float s = dinv[row];
            ushort4 o;
            o.x = f2bf(acc[i][0] * s);
            o.y = f2bf(acc[i][1] * s);
            o.z = f2bf(acc[i][2] * s);
            o.w = f2bf(acc[i][3] * s);
            *(ushort4*)&g1[row * 128 + c0] = o;
        }
    }
}

// a1[v] = bf16(relu(dinv[v]*(g1[v] + sum_{s in Nin(v)} g1[s]) + b1))
// 64 lanes per node (2 cols each), 4 nodes per block
__global__ __launch_bounds__(256) void k_agg1(const ushort_t* __restrict__ g1,
                                              const float* __restrict__ dinv,
                                              const float* __restrict__ b1,
                                              const int* __restrict__ row_start,
                                              const int* __restrict__ csr_src,
                                              ushort_t* __restrict__ a1) {
    int v = blockIdx.x * 4 + (threadIdx.x >> 6);
    int c2 = (threadIdx.x & 63) * 2;
    uint w = *(const uint*)(g1 + (size_t)v * 128 + c2);
    float s0 = bf2f(w & 0xffffu), s1 = bf2f(w >> 16);
    int jb = row_start[v], je = row_start[v + 1];
    for (int j = jb; j < je; j++) {
        int s = csr_src[j];
        uint u = *(const uint*)(g1 + (size_t)s * 128 + c2);
        s0 += bf2f(u & 0xffffu);
        s1 += bf2f(u >> 16);
    }
    float d = dinv[v];
    float o0 = fmaxf(d * s0 + b1[c2], 0.0f);
    float o1 = fmaxf(d * s1 + b1[c2 + 1], 0.0f);
    uint ow = (uint)f2bf(o0) | ((uint)f2bf(o1) << 16);
    *(uint*)(a1 + (size_t)v * 128 + c2) = ow;
}

// g2 = (a1 @ W2) * dinv[row]; a1 [N,128] bf16, W2 [128,32] f32, g2 f32
__global__ __launch_bounds__(256) void k_gemm2(const ushort_t* __restrict__ a1,
                                               const float* __restrict__ W,
                                               const float* __restrict__ dinv,
                                               float* __restrict__ g2) {
    __shared__ __align__(16) float Ws[128][32];
    __shared__ float Xs[128][65];
    int t = threadIdx.x;
    int row0 = blockIdx.x * 128;
    #pragma unroll
    for (int i = 0; i < 16; i++) {
        int f = i * 256 + t;
        Ws[f >> 5][f & 31] = W[f];
    }
    int c0 = (t & 7) * 4;
    int r0 = (t >> 3) * 4;
    float acc[4][4] = {};
    for (int k0 = 0; k0 < 128; k0 += 64) {
        #pragma unroll
        for (int i = 0; i < 16; i++) {
            int f = i * 256 + t;          // 0..4095
            int r = f >> 5;               // 0..127
            int kk2 = (f & 31) * 2;       // 0,2,..,62
            int row = row0 + r;
            uint w = (row < N_NODES) ? *(const uint*)(a1 + (size_t)row * 128 + k0 + kk2) : 0u;
            Xs[r][kk2]     = bf2f(w & 0xffffu);
            Xs[r][kk2 + 1] = bf2f(w >> 16);
        }
        __syncthreads();
        #pragma unroll
        for (int kk = 0; kk < 64; kk++) {
            float4 b = *(const float4*)&Ws[k0 + kk][c0];
            #pragma unroll
            for (int i = 0; i < 4; i++) {
                float a = Xs[r0 + i][kk];
                acc[i][0] += a * b.x;
                acc[i][1] += a * b.y;
                acc[i][2] += a * b.z;
                acc[i][3] += a * b.w;
            }
        }
        __syncthreads();
    }
    #pragma unroll
    for (int i = 0; i < 4; i++) {
        int row = row0 + r0 + i;
        if (row < N_NODES) {
            float s = dinv[row];
            float4 o;
            o.x = acc[i][0] * s; o.y = acc[i][1] * s;
            o.z = acc[i][2] * s; o.w = acc[i][3] * s;
            *(float4*)&g2[row * 32 + c0] = o;
        }
    }
}

// out[v] = log_softmax(dinv[v]*(g2[v] + sum g2[s]) + b2)
__global__ __launch_bounds__(256) void k_agg2(const float* __restrict__ g2,
                                              const float* __restrict__ dinv,
                                              const float* __restrict__ b2,
                                              const int* __restrict__ row_start,
                                              const int* __restrict__ csr_src,
                                              float* __restrict__ out) {
    int v = blockIdx.x * 8 + (threadIdx.x >> 5);
    int c = threadIdx.x & 31;
    float acc = g2[(size_t)v * 32 + c];
    int jb = row_start[v], je = row_start[v + 1];
    for (int j = jb; j < je; j++) {
        int s = csr_src[j];
        acc += g2[(size_t)s * 32 + c];
    }
    float z = dinv[v] * acc + b2[c];
    float m = z;
    #pragma unroll
    for (int off = 16; off >= 1; off >>= 1) m = fmaxf(m, __shfl_xor(m, off));
    float e = __expf(z - m);
    float ssum = e;
    #pragma unroll
    for (int off = 16; off >= 1; off >>= 1) ssum += __shfl_xor(ssum, off);
    out[(size_t)v * 32 + c] = (z - m) - __logf(ssum);
}

// ---------------- launch ----------------

extern "C" void kernel_launch(void* const* d_in, const int* in_sizes, int n_in,
                              void* d_out, int out_size, void* d_ws, size_t ws_size,
                              hipStream_t stream) {
    const float* x  = (const float*)d_in[0];
    const int*   ei = (const int*)d_in[1];
    const float* W1 = (const float*)d_in[2];
    const float* b1 = (const float*)d_in[3];
    const float* W2 = (const float*)d_in[4];
    const float* b2 = (const float*)d_in[5];
    float* out = (float*)d_out;

    char* ws = (char*)d_ws;
    size_t off = 0;
    auto alloc = [&](size_t bytes) {
        void* p = ws + off;
        off = (off + bytes + 255) & ~255ULL;
        return p;
    };
    // zeroed region first (single memset): flag, deg, cursor
    int* flag      = (int*)alloc(4);
    int* deg       = (int*)alloc((size_t)N_NODES * 4);
    int* cursor    = (int*)alloc((size_t)N_NODES * 4);
    size_t zero_bytes = off;
    int*   row_start = (int*)alloc((size_t)(N_NODES + 1) * 4);
    int*   blk       = (int*)alloc(256 * 4);
    float* dinv      = (float*)alloc((size_t)N_NODES * 4);
    int*   csr_src   = (int*)alloc((size_t)N_EDGES * 4);
    ushort_t* g1     = (ushort_t*)alloc((size_t)N_NODES * 128 * 2);  // reused as g2 (f32, 12.8MB<25.6MB)
    ushort_t* a1     = (ushort_t*)alloc((size_t)N_NODES * 128 * 2);
    float* g2 = (float*)g1;  // g1 dead after k_agg1

    hipMemsetAsync(flag, 0, zero_bytes, stream);

    int nb = (N_NODES + 1023) / 1024;  // 98
    k_detect<<<1, 256, 0, stream>>>(ei, flag);
    k_hist<<<(N_EDGES + 255) / 256, 256, 0, stream>>>(ei, flag, deg);
    k_dinv<<<(N_NODES + 255) / 256, 256, 0, stream>>>(deg, dinv);
    k_scan_local<<<nb, 256, 0, stream>>>(deg, row_start, blk);
    k_scan_blk<<<1, 128, 0, stream>>>(blk, nb);
    k_scan_add<<<nb, 256, 0, stream>>>(row_start, blk);
    k_fill<<<(N_EDGES + 255) / 256, 256, 0, stream>>>(ei, flag, row_start, cursor, csr_src);
    k_gemm1<<<(N_NODES + 63) / 64, 256, 0, stream>>>(x, W1, dinv, g1);
    k_agg1<<<N_NODES / 4, 256, 0, stream>>>(g1, dinv, b1, row_start, csr_src, a1);
    k_gemm2<<<(N_NODES + 127) / 128, 256, 0, stream>>>(a1, W2, dinv, g2);
    k_agg2<<<N_NODES / 8, 256, 0, stream>>>(g2, dinv, b2, row_start, csr_src, out);
}

// Round 3
// 438.252 us; speedup vs baseline: 1.2098x; 1.2098x over previous
//
#include <hip/hip_runtime.h>
#include <hip/hip_bf16.h>
#include <math.h>

#define N_NODES 100000
#define N_EDGES 1600000

typedef unsigned int uint;
typedef unsigned short ushort_t;

__device__ __forceinline__ float bf2f(uint h) {
    union { uint u; float f; } x; x.u = h << 16; return x.f;
}
__device__ __forceinline__ unsigned short f2bf(float f) {
    union { float f; uint u; } x; x.f = f;
    uint u = x.u;
    return (unsigned short)((u + 0x7fffu + ((u >> 16) & 1u)) >> 16);  // RNE
}

// ---------------- edge dtype detection ----------------
__global__ void k_detect(const int* __restrict__ ei, int* __restrict__ flag) {
    int t = threadIdx.x;
    int v = ei[2 * t + 1] | ei[2 * (t + 256) + 1];
    if (v) atomicOr(flag, 1);  // 1 => int32 layout
}

__device__ __forceinline__ int edge_at(const int* __restrict__ ei, int is32, long long idx) {
    return is32 ? ei[idx] : (int)(((const long long*)ei)[idx]);
}

// ---------------- CSR build ----------------

__global__ void k_hist(const int* __restrict__ ei, const int* __restrict__ flag,
                       int* __restrict__ deg) {
    int e = blockIdx.x * blockDim.x + threadIdx.x;
    int is32 = *flag;
    if (e < N_EDGES) atomicAdd(&deg[edge_at(ei, is32, (long long)N_EDGES + e)], 1);
}

__global__ void k_dinv(const int* __restrict__ deg, float* __restrict__ dinv) {
    int i = blockIdx.x * blockDim.x + threadIdx.x;
    if (i < N_NODES) dinv[i] = rsqrtf((float)(deg[i] + 1));  // +1 self loop
}

__global__ void k_scan_local(const int* __restrict__ deg, int* __restrict__ row_start,
                             int* __restrict__ blk) {
    __shared__ int sums[256];
    int t = threadIdx.x;
    int base = blockIdx.x * 1024;
    int idx = base + t * 4;
    int v0 = 0, v1 = 0, v2 = 0, v3 = 0;
    if (idx + 3 < N_NODES) {
        int4 v = *(const int4*)(deg + idx);
        v0 = v.x; v1 = v.y; v2 = v.z; v3 = v.w;
    } else {
        if (idx + 0 < N_NODES) v0 = deg[idx + 0];
        if (idx + 1 < N_NODES) v1 = deg[idx + 1];
        if (idx + 2 < N_NODES) v2 = deg[idx + 2];
        if (idx + 3 < N_NODES) v3 = deg[idx + 3];
    }
    int tsum = v0 + v1 + v2 + v3;
    sums[t] = tsum;
    __syncthreads();
    int val = tsum;
    for (int off = 1; off < 256; off <<= 1) {
        int tmp = (t >= off) ? sums[t - off] : 0;
        __syncthreads();
        val += tmp;
        sums[t] = val;
        __syncthreads();
    }
    int excl = val - tsum;
    if (t == 255) blk[blockIdx.x] = val;
    if (idx + 0 < N_NODES) row_start[idx + 0] = excl;
    if (idx + 1 < N_NODES) row_start[idx + 1] = excl + v0;
    if (idx + 2 < N_NODES) row_start[idx + 2] = excl + v0 + v1;
    if (idx + 3 < N_NODES) row_start[idx + 3] = excl + v0 + v1 + v2;
}

__global__ void k_scan_blk(int* __restrict__ blk, int nb) {
    __shared__ int s[128];
    int t = threadIdx.x;
    int v = (t < nb) ? blk[t] : 0;
    s[t] = v;
    __syncthreads();
    int val = v;
    for (int off = 1; off < 128; off <<= 1) {
        int tmp = (t >= off) ? s[t - off] : 0;
        __syncthreads();
        val += tmp;
        s[t] = val;
        __syncthreads();
    }
    if (t < nb) blk[t] = val - v;  // exclusive
}

// also writes cursor = row_start (so k_fill's atomicAdd returns the slot directly)
__global__ void k_scan_add(int* __restrict__ row_start, const int* __restrict__ blk,
                           int* __restrict__ cursor) {
    int t = threadIdx.x;
    int base = blockIdx.x * 1024;
    int add = blk[blockIdx.x];
    int idx = base + t * 4;
    #pragma unroll
    for (int i = 0; i < 4; i++)
        if (idx + i < N_NODES) {
            int v = row_start[idx + i] + add;
            row_start[idx + i] = v;
            cursor[idx + i] = v;
        }
    if (blockIdx.x == 0 && t == 0) row_start[N_NODES] = N_EDGES;
}

__global__ void k_fill(const int* __restrict__ ei, const int* __restrict__ flag,
                       int* __restrict__ cursor, int* __restrict__ csr_src) {
    int e = blockIdx.x * blockDim.x + threadIdx.x;
    int is32 = *flag;
    if (e < N_EDGES) {
        int d = edge_at(ei, is32, (long long)N_EDGES + e);
        int s = edge_at(ei, is32, e);
        int pos = atomicAdd(&cursor[d], 1);
        csr_src[pos] = s;
    }
}

// ---------------- Layer compute ----------------

// g1 = bf16((x @ W1) * dinv[row]); x [N,128] f32, W1 [128,128] f32
__global__ __launch_bounds__(256) void k_gemm1(const float* __restrict__ x,
                                               const float* __restrict__ W,
                                               const float* __restrict__ dinv,
                                               ushort_t* __restrict__ g1) {
    __shared__ __align__(16) float Ws[32][128];
    __shared__ float Xs[64][33];
    int t = threadIdx.x;
    int row0 = blockIdx.x * 64;
    int c0 = (t & 31) * 4;
    int r0 = (t >> 5) * 8;
    float acc[8][4] = {};
    for (int k0 = 0; k0 < 128; k0 += 32) {
        #pragma unroll
        for (int i = 0; i < 16; i++) {
            int f = i * 256 + t;
            int kk = f >> 7, c = f & 127;
            Ws[kk][c] = W[(k0 + kk) * 128 + c];
        }
        #pragma unroll
        for (int i = 0; i < 8; i++) {
            int f = i * 256 + t;
            int r = f >> 5, kk = f & 31;
            int row = row0 + r;
            Xs[r][kk] = (row < N_NODES) ? x[row * 128 + k0 + kk] : 0.0f;
        }
        __syncthreads();
        #pragma unroll
        for (int kk = 0; kk < 32; kk++) {
            float4 b = *(const float4*)&Ws[kk][c0];
            #pragma unroll
            for (int i = 0; i < 8; i++) {
                float a = Xs[r0 + i][kk];
                acc[i][0] += a * b.x;
                acc[i][1] += a * b.y;
                acc[i][2] += a * b.z;
                acc[i][3] += a * b.w;
            }
        }
        __syncthreads();
    }
    #pragma unroll
    for (int i = 0; i < 8; i++) {
        int row = row0 + r0 + i;
        if (row < N_NODES) {
            float s = dinv[row];
            ushort4 o;
            o.x = f2bf(acc[i][0] * s);
            o.y = f2bf(acc[i][1] * s);
            o.z = f2bf(acc[i][2] * s);
            o.w = f2bf(acc[i][3] * s);
            *(ushort4*)&g1[row * 128 + c0] = o;
        }
    }
}

// a1[v] = bf16(relu(dinv[v]*(g1[v] + sum_{s in Nin(v)} g1[s]) + b1))
// 64 lanes per node (2 cols each, packed in one uint), 4 nodes per block.
// 8-deep unrolled gather for memory-level parallelism.
__global__ __launch_bounds__(256) void k_agg1(const ushort_t* __restrict__ g1,
                                              const float* __restrict__ dinv,
                                              const float* __restrict__ b1,
                                              const int* __restrict__ row_start,
                                              const int* __restrict__ csr_src,
                                              ushort_t* __restrict__ a1) {
    int v = blockIdx.x * 4 + (threadIdx.x >> 6);
    int col = threadIdx.x & 63;
    const uint* __restrict__ g = (const uint*)g1;
    uint w = g[(size_t)v * 64 + col];
    float s0 = bf2f(w & 0xffffu), s1 = bf2f(w >> 16);
    int jb = row_start[v], je = row_start[v + 1];
    int j = jb;
    for (; j + 8 <= je; j += 8) {
        int i0 = csr_src[j + 0], i1 = csr_src[j + 1];
        int i2 = csr_src[j + 2], i3 = csr_src[j + 3];
        int i4 = csr_src[j + 4], i5 = csr_src[j + 5];
        int i6 = csr_src[j + 6], i7 = csr_src[j + 7];
        uint u0 = g[(size_t)i0 * 64 + col];
        uint u1 = g[(size_t)i1 * 64 + col];
        uint u2 = g[(size_t)i2 * 64 + col];
        uint u3 = g[(size_t)i3 * 64 + col];
        uint u4 = g[(size_t)i4 * 64 + col];
        uint u5 = g[(size_t)i5 * 64 + col];
        uint u6 = g[(size_t)i6 * 64 + col];
        uint u7 = g[(size_t)i7 * 64 + col];
        s0 += bf2f(u0 & 0xffffu) + bf2f(u1 & 0xffffu) + bf2f(u2 & 0xffffu) + bf2f(u3 & 0xffffu)
            + bf2f(u4 & 0xffffu) + bf2f(u5 & 0xffffu) + bf2f(u6 & 0xffffu) + bf2f(u7 & 0xffffu);
        s1 += bf2f(u0 >> 16) + bf2f(u1 >> 16) + bf2f(u2 >> 16) + bf2f(u3 >> 16)
            + bf2f(u4 >> 16) + bf2f(u5 >> 16) + bf2f(u6 >> 16) + bf2f(u7 >> 16);
    }
    for (; j < je; j++) {
        int s = csr_src[j];
        uint u = g[(size_t)s * 64 + col];
        s0 += bf2f(u & 0xffffu);
        s1 += bf2f(u >> 16);
    }
    int c2 = col * 2;
    float d = dinv[v];
    float o0 = fmaxf(d * s0 + b1[c2], 0.0f);
    float o1 = fmaxf(d * s1 + b1[c2 + 1], 0.0f);
    uint ow = (uint)f2bf(o0) | ((uint)f2bf(o1) << 16);
    *(uint*)(a1 + (size_t)v * 128 + c2) = ow;
}

// g2 = (a1 @ W2) * dinv[row]; a1 [N,128] bf16, W2 [128,32] f32, g2 f32
__global__ __launch_bounds__(256) void k_gemm2(const ushort_t* __restrict__ a1,
                                               const float* __restrict__ W,
                                               const float* __restrict__ dinv,
                                               float* __restrict__ g2) {
    __shared__ __align__(16) float Ws[128][32];
    __shared__ float Xs[128][65];
    int t = threadIdx.x;
    int row0 = blockIdx.x * 128;
    #pragma unroll
    for (int i = 0; i < 16; i++) {
        int f = i * 256 + t;
        Ws[f >> 5][f & 31] = W[f];
    }
    int c0 = (t & 7) * 4;
    int r0 = (t >> 3) * 4;
    float acc[4][4] = {};
    for (int k0 = 0; k0 < 128; k0 += 64) {
        #pragma unroll
        for (int i = 0; i < 16; i++) {
            int f = i * 256 + t;          // 0..4095
            int r = f >> 5;               // 0..127
            int kk2 = (f & 31) * 2;       // 0,2,..,62
            int row = row0 + r;
            uint w = (row < N_NODES) ? *(const uint*)(a1 + (size_t)row * 128 + k0 + kk2) : 0u;
            Xs[r][kk2]     = bf2f(w & 0xffffu);
            Xs[r][kk2 + 1] = bf2f(w >> 16);
        }
        __syncthreads();
        #pragma unroll
        for (int kk = 0; kk < 64; kk++) {
            float4 b = *(const float4*)&Ws[k0 + kk][c0];
            #pragma unroll
            for (int i = 0; i < 4; i++) {
                float a = Xs[r0 + i][kk];
                acc[i][0] += a * b.x;
                acc[i][1] += a * b.y;
                acc[i][2] += a * b.z;
                acc[i][3] += a * b.w;
            }
        }
        __syncthreads();
    }
    #pragma unroll
    for (int i = 0; i < 4; i++) {
        int row = row0 + r0 + i;
        if (row < N_NODES) {
            float s = dinv[row];
            float4 o;
            o.x = acc[i][0] * s; o.y = acc[i][1] * s;
            o.z = acc[i][2] * s; o.w = acc[i][3] * s;
            *(float4*)&g2[row * 32 + c0] = o;
        }
    }
}

// out[v] = log_softmax(dinv[v]*(g2[v] + sum g2[s]) + b2), 8-deep unrolled gather
__global__ __launch_bounds__(256) void k_agg2(const float* __restrict__ g2,
                                              const float* __restrict__ dinv,
                                              const float* __restrict__ b2,
                                              const int* __restrict__ row_start,
                                              const int* __restrict__ csr_src,
                                              float* __restrict__ out) {
    int v = blockIdx.x * 8 + (threadIdx.x >> 5);
    int c = threadIdx.x & 31;
    float acc = g2[(size_t)v * 32 + c];
    int jb = row_start[v], je = row_start[v + 1];
    int j = jb;
    for (; j + 8 <= je; j += 8) {
        int i0 = csr_src[j + 0], i1 = csr_src[j + 1];
        int i2 = csr_src[j + 2], i3 = csr_src[j + 3];
        int i4 = csr_src[j + 4], i5 = csr_src[j + 5];
        int i6 = csr_src[j + 6], i7 = csr_src[j + 7];
        float a0 = g2[(size_t)i0 * 32 + c];
        float a1v = g2[(size_t)i1 * 32 + c];
        float a2 = g2[(size_t)i2 * 32 + c];
        float a3 = g2[(size_t)i3 * 32 + c];
        float a4 = g2[(size_t)i4 * 32 + c];
        float a5 = g2[(size_t)i5 * 32 + c];
        float a6 = g2[(size_t)i6 * 32 + c];
        float a7 = g2[(size_t)i7 * 32 + c];
        acc += a0 + a1v + a2 + a3 + a4 + a5 + a6 + a7;
    }
    for (; j < je; j++) {
        int s = csr_src[j];
        acc += g2[(size_t)s * 32 + c];
    }
    float z = dinv[v] * acc + b2[c];
    float m = z;
    #pragma unroll
    for (int off = 16; off >= 1; off >>= 1) m = fmaxf(m, __shfl_xor(m, off));
    float e = __expf(z - m);
    float ssum = e;
    #pragma unroll
    for (int off = 16; off >= 1; off >>= 1) ssum += __shfl_xor(ssum, off);
    out[(size_t)v * 32 + c] = (z - m) - __logf(ssum);
}

// ---------------- launch ----------------

extern "C" void kernel_launch(void* const* d_in, const int* in_sizes, int n_in,
                              void* d_out, int out_size, void* d_ws, size_t ws_size,
                              hipStream_t stream) {
    const float* x  = (const float*)d_in[0];
    const int*   ei = (const int*)d_in[1];
    const float* W1 = (const float*)d_in[2];
    const float* b1 = (const float*)d_in[3];
    const float* W2 = (const float*)d_in[4];
    const float* b2 = (const float*)d_in[5];
    float* out = (float*)d_out;

    char* ws = (char*)d_ws;
    size_t off = 0;
    auto alloc = [&](size_t bytes) {
        void* p = ws + off;
        off = (off + bytes + 255) & ~255ULL;
        return p;
    };
    // zeroed region first (single memset): flag, deg
    int* flag      = (int*)alloc(4);
    int* deg       = (int*)alloc((size_t)N_NODES * 4);
    size_t zero_bytes = off;
    int*   cursor    = (int*)alloc((size_t)N_NODES * 4);
    int*   row_start = (int*)alloc((size_t)(N_NODES + 1) * 4);
    int*   blk       = (int*)alloc(256 * 4);
    float* dinv      = (float*)alloc((size_t)N_NODES * 4);
    int*   csr_src   = (int*)alloc((size_t)N_EDGES * 4);
    ushort_t* g1     = (ushort_t*)alloc((size_t)N_NODES * 128 * 2);  // reused as g2 (f32, 12.8MB<25.6MB)
    ushort_t* a1     = (ushort_t*)alloc((size_t)N_NODES * 128 * 2);
    float* g2 = (float*)g1;  // g1 dead after k_agg1

    hipMemsetAsync(flag, 0, zero_bytes, stream);

    int nb = (N_NODES + 1023) / 1024;  // 98
    k_detect<<<1, 256, 0, stream>>>(ei, flag);
    k_hist<<<(N_EDGES + 255) / 256, 256, 0, stream>>>(ei, flag, deg);
    k_dinv<<<(N_NODES + 255) / 256, 256, 0, stream>>>(deg, dinv);
    k_scan_local<<<nb, 256, 0, stream>>>(deg, row_start, blk);
    k_scan_blk<<<1, 128, 0, stream>>>(blk, nb);
    k_scan_add<<<nb, 256, 0, stream>>>(row_start, blk, cursor);
    k_fill<<<(N_EDGES + 255) / 256, 256, 0, stream>>>(ei, flag, cursor, csr_src);
    k_gemm1<<<(N_NODES + 63) / 64, 256, 0, stream>>>(x, W1, dinv, g1);
    k_agg1<<<N_NODES / 4, 256, 0, stream>>>(g1, dinv, b1, row_start, csr_src, a1);
    k_gemm2<<<(N_NODES + 127) / 128, 256, 0, stream>>>(a1, W2, dinv, g2);
    k_agg2<<<N_NODES / 8, 256, 0, stream>>>(g2, dinv, b2, row_start, csr_src, out);
}

// Round 4
// 290.579 us; speedup vs baseline: 1.8247x; 1.5082x over previous
//
#include <hip/hip_runtime.h>
#include <hip/hip_bf16.h>
#include <math.h>

#define N_NODES 100000
#define N_EDGES 1600000
#define NB 196        // buckets of 512 nodes: 196*512 = 100352
#define CAP 16000     // per-bucket capacity (mean 8163, sigma ~90)
#define CHUNK 4096

typedef unsigned int uint;
typedef unsigned short ushort_t;

__device__ __forceinline__ float bf2f(uint h) {
    union { uint u; float f; } x; x.u = h << 16; return x.f;
}
__device__ __forceinline__ unsigned short f2bf(float f) {
    union { float f; uint u; } x; x.f = f;
    uint u = x.u;
    return (unsigned short)((u + 0x7fffu + ((u >> 16) & 1u)) >> 16);  // RNE
}

// ---------------- edge dtype detection ----------------
__global__ void k_detect(const int* __restrict__ ei, int* __restrict__ flag) {
    int t = threadIdx.x;
    int v = ei[2 * t + 1] | ei[2 * (t + 256) + 1];
    if (v) atomicOr(flag, 1);  // 1 => int32 layout
}

__device__ __forceinline__ int edge_at(const int* __restrict__ ei, int is32, long long idx) {
    return is32 ? ei[idx] : (int)(((const long long*)ei)[idx]);
}

// ---------------- CSR build via LDS-staged counting sort ----------------

// Pass A: bucket edges by dst>>9 into per-bucket regions of buf (coalesced flush).
__global__ __launch_bounds__(256) void k_bucket(const int* __restrict__ ei,
                                                const int* __restrict__ flag,
                                                int* __restrict__ cnt,
                                                uint2* __restrict__ buf) {
    __shared__ uint2 stage[CHUNK];
    __shared__ unsigned char bid[CHUNK];
    __shared__ int lcnt[256], ls[256], lbase[256], gbase[256];
    int t = threadIdx.x;
    int is32 = *flag;
    lcnt[t] = 0;
    __syncthreads();
    int base = blockIdx.x * CHUNK;
    int srcv[16], dstv[16], offv[16];
    #pragma unroll
    for (int i = 0; i < 16; i++) {
        int e = base + i * 256 + t;
        if (e < N_EDGES) {
            srcv[i] = edge_at(ei, is32, e);
            dstv[i] = edge_at(ei, is32, (long long)N_EDGES + e);
            offv[i] = atomicAdd(&lcnt[dstv[i] >> 9], 1);
        } else {
            offv[i] = -1;
        }
    }
    __syncthreads();
    int c = lcnt[t];
    ls[t] = c;
    __syncthreads();
    int val = c;
    for (int off = 1; off < 256; off <<= 1) {
        int tmp = (t >= off) ? ls[t - off] : 0;
        __syncthreads();
        val += tmp;
        ls[t] = val;
        __syncthreads();
    }
    lbase[t] = val - c;  // exclusive
    if (c > 0) gbase[t] = atomicAdd(&cnt[t], c); else gbase[t] = 0;
    __syncthreads();
    int total = ls[255];
    #pragma unroll
    for (int i = 0; i < 16; i++) {
        if (offv[i] >= 0) {
            int b = dstv[i] >> 9;
            int p = lbase[b] + offv[i];
            stage[p] = make_uint2((uint)srcv[i], (uint)dstv[i]);
            bid[p] = (unsigned char)b;
        }
    }
    __syncthreads();
    for (int idx = t; idx < total; idx += 256) {
        int b = bid[idx];
        int r = gbase[b] + (idx - lbase[b]);
        if (r < CAP) buf[(size_t)b * CAP + r] = stage[idx];
    }
}

// Scan of 196 bucket counts -> bucket bases. Also writes row_start[N].
__global__ void k_bscan(const int* __restrict__ cnt, int* __restrict__ bbase,
                        int* __restrict__ row_start) {
    __shared__ int s[256];
    int t = threadIdx.x;
    int v = (t < NB) ? cnt[t] : 0;
    s[t] = v;
    __syncthreads();
    int val = v;
    for (int off = 1; off < 256; off <<= 1) {
        int tmp = (t >= off) ? s[t - off] : 0;
        __syncthreads();
        val += tmp;
        s[t] = val;
        __syncthreads();
    }
    if (t < NB) bbase[t] = val - v;
    if (t == 0) row_start[N_NODES] = N_EDGES;
}

// Pass B: one WG per bucket. Count per-node deg in LDS, scan, emit row_start +
// dinv, then scatter csr_src within the bucket's (L2-resident) window.
__global__ __launch_bounds__(256) void k_build(const uint2* __restrict__ buf,
                                               const int* __restrict__ cnt,
                                               const int* __restrict__ bbase,
                                               int* __restrict__ row_start,
                                               float* __restrict__ dinv,
                                               int* __restrict__ csr_src) {
    __shared__ int ldeg[512], lexc[512], lcur[512], s[256];
    int t = threadIdx.x;
    int b = blockIdx.x;
    int n0 = b << 9;
    int nn = min(512, N_NODES - n0);
    int ne = min(cnt[b], CAP);
    const uint2* __restrict__ in = buf + (size_t)b * CAP;
    int obase = bbase[b];
    ldeg[t] = 0; ldeg[t + 256] = 0;
    lcur[t] = 0; lcur[t + 256] = 0;
    __syncthreads();
    for (int idx = t; idx < ne; idx += 256) {
        uint2 p = in[idx];
        atomicAdd(&ldeg[p.y - n0], 1);
    }
    __syncthreads();
    int v = ldeg[2 * t] + ldeg[2 * t + 1];
    s[t] = v;
    __syncthreads();
    int val = v;
    for (int off = 1; off < 256; off <<= 1) {
        int tmp = (t >= off) ? s[t - off] : 0;
        __syncthreads();
        val += tmp;
        s[t] = val;
        __syncthreads();
    }
    int excl = val - v;
    lexc[2 * t] = excl;
    lexc[2 * t + 1] = excl + ldeg[2 * t];
    __syncthreads();
    for (int i = t; i < nn; i += 256) {
        row_start[n0 + i] = obase + lexc[i];
        dinv[n0 + i] = rsqrtf((float)(ldeg[i] + 1));  // +1 self loop
    }
    __syncthreads();
    for (int idx = t; idx < ne; idx += 256) {
        uint2 p = in[idx];
        int dl = p.y - n0;
        int pos = obase + lexc[dl] + atomicAdd(&lcur[dl], 1);
        csr_src[pos] = (int)p.x;
    }
}

// ---------------- Layer compute ----------------

// g1 = bf16((x @ W1) * dinv[row]); x [N,128] f32, W1 [128,128] f32
__global__ __launch_bounds__(256) void k_gemm1(const float* __restrict__ x,
                                               const float* __restrict__ W,
                                               const float* __restrict__ dinv,
                                               ushort_t* __restrict__ g1) {
    __shared__ __align__(16) float Ws[32][128];
    __shared__ float Xs[64][33];
    int t = threadIdx.x;
    int row0 = blockIdx.x * 64;
    int c0 = (t & 31) * 4;
    int r0 = (t >> 5) * 8;
    float acc[8][4] = {};
    for (int k0 = 0; k0 < 128; k0 += 32) {
        #pragma unroll
        for (int i = 0; i < 16; i++) {
            int f = i * 256 + t;
            int kk = f >> 7, c = f & 127;
            Ws[kk][c] = W[(k0 + kk) * 128 + c];
        }
        #pragma unroll
        for (int i = 0; i < 8; i++) {
            int f = i * 256 + t;
            int r = f >> 5, kk = f & 31;
            int row = row0 + r;
            Xs[r][kk] = (row < N_NODES) ? x[row * 128 + k0 + kk] : 0.0f;
        }
        __syncthreads();
        #pragma unroll
        for (int kk = 0; kk < 32; kk++) {
            float4 b = *(const float4*)&Ws[kk][c0];
            #pragma unroll
            for (int i = 0; i < 8; i++) {
                float a = Xs[r0 + i][kk];
                acc[i][0] += a * b.x;
                acc[i][1] += a * b.y;
                acc[i][2] += a * b.z;
                acc[i][3] += a * b.w;
            }
        }
        __syncthreads();
    }
    #pragma unroll
    for (int i = 0; i < 8; i++) {
        int row = row0 + r0 + i;
        if (row < N_NODES) {
            float s = dinv[row];
            ushort4 o;
            o.x = f2bf(acc[i][0] * s);
            o.y = f2bf(acc[i][1] * s);
            o.z = f2bf(acc[i][2] * s);
            o.w = f2bf(acc[i][3] * s);
            *(ushort4*)&g1[row * 128 + c0] = o;
        }
    }
}

// a1[v] = bf16(relu(dinv[v]*(g1[v] + sum_{s in Nin(v)} g1[s]) + b1))
__global__ __launch_bounds__(256) void k_agg1(const ushort_t* __restrict__ g1,
                                              const float* __restrict__ dinv,
                                              const float* __restrict__ b1,
                                              const int* __restrict__ row_start,
                                              const int* __restrict__ csr_src,
                                              ushort_t* __restrict__ a1) {
    int v = blockIdx.x * 4 + (threadIdx.x >> 6);
    int col = threadIdx.x & 63;
    const uint* __restrict__ g = (const uint*)g1;
    uint w = g[(size_t)v * 64 + col];
    float s0 = bf2f(w & 0xffffu), s1 = bf2f(w >> 16);
    int jb = row_start[v], je = row_start[v + 1];
    int j = jb;
    for (; j + 8 <= je; j += 8) {
        int i0 = csr_src[j + 0], i1 = csr_src[j + 1];
        int i2 = csr_src[j + 2], i3 = csr_src[j + 3];
        int i4 = csr_src[j + 4], i5 = csr_src[j + 5];
        int i6 = csr_src[j + 6], i7 = csr_src[j + 7];
        uint u0 = g[(size_t)i0 * 64 + col];
        uint u1 = g[(size_t)i1 * 64 + col];
        uint u2 = g[(size_t)i2 * 64 + col];
        uint u3 = g[(size_t)i3 * 64 + col];
        uint u4 = g[(size_t)i4 * 64 + col];
        uint u5 = g[(size_t)i5 * 64 + col];
        uint u6 = g[(size_t)i6 * 64 + col];
        uint u7 = g[(size_t)i7 * 64 + col];
        s0 += bf2f(u0 & 0xffffu) + bf2f(u1 & 0xffffu) + bf2f(u2 & 0xffffu) + bf2f(u3 & 0xffffu)
            + bf2f(u4 & 0xffffu) + bf2f(u5 & 0xffffu) + bf2f(u6 & 0xffffu) + bf2f(u7 & 0xffffu);
        s1 += bf2f(u0 >> 16) + bf2f(u1 >> 16) + bf2f(u2 >> 16) + bf2f(u3 >> 16)
            + bf2f(u4 >> 16) + bf2f(u5 >> 16) + bf2f(u6 >> 16) + bf2f(u7 >> 16);
    }
    for (; j < je; j++) {
        int s = csr_src[j];
        uint u = g[(size_t)s * 64 + col];
        s0 += bf2f(u & 0xffffu);
        s1 += bf2f(u >> 16);
    }
    int c2 = col * 2;
    float d = dinv[v];
    float o0 = fmaxf(d * s0 + b1[c2], 0.0f);
    float o1 = fmaxf(d * s1 + b1[c2 + 1], 0.0f);
    uint ow = (uint)f2bf(o0) | ((uint)f2bf(o1) << 16);
    *(uint*)(a1 + (size_t)v * 128 + c2) = ow;
}

// g2 = (a1 @ W2) * dinv[row]; a1 [N,128] bf16, W2 [128,32] f32, g2 f32
__global__ __launch_bounds__(256) void k_gemm2(const ushort_t* __restrict__ a1,
                                               const float* __restrict__ W,
                                               const float* __restrict__ dinv,
                                               float* __restrict__ g2) {
    __shared__ __align__(16) float Ws[128][32];
    __shared__ float Xs[128][65];
    int t = threadIdx.x;
    int row0 = blockIdx.x * 128;
    #pragma unroll
    for (int i = 0; i < 16; i++) {
        int f = i * 256 + t;
        Ws[f >> 5][f & 31] = W[f];
    }
    int c0 = (t & 7) * 4;
    int r0 = (t >> 3) * 4;
    float acc[4][4] = {};
    for (int k0 = 0; k0 < 128; k0 += 64) {
        #pragma unroll
        for (int i = 0; i < 16; i++) {
            int f = i * 256 + t;          // 0..4095
            int r = f >> 5;               // 0..127
            int kk2 = (f & 31) * 2;       // 0,2,..,62
            int row = row0 + r;
            uint w = (row < N_NODES) ? *(const uint*)(a1 + (size_t)row * 128 + k0 + kk2) : 0u;
            Xs[r][kk2]     = bf2f(w & 0xffffu);
            Xs[r][kk2 + 1] = bf2f(w >> 16);
        }
        __syncthreads();
        #pragma unroll
        for (int kk = 0; kk < 64; kk++) {
            float4 b = *(const float4*)&Ws[k0 + kk][c0];
            #pragma unroll
            for (int i = 0; i < 4; i++) {
                float a = Xs[r0 + i][kk];
                acc[i][0] += a * b.x;
                acc[i][1] += a * b.y;
                acc[i][2] += a * b.z;
                acc[i][3] += a * b.w;
            }
        }
        __syncthreads();
    }
    #pragma unroll
    for (int i = 0; i < 4; i++) {
        int row = row0 + r0 + i;
        if (row < N_NODES) {
            float s = dinv[row];
            float4 o;
            o.x = acc[i][0] * s; o.y = acc[i][1] * s;
            o.z = acc[i][2] * s; o.w = acc[i][3] * s;
            *(float4*)&g2[row * 32 + c0] = o;
        }
    }
}

// out[v] = log_softmax(dinv[v]*(g2[v] + sum g2[s]) + b2)
__global__ __launch_bounds__(256) void k_agg2(const float* __restrict__ g2,
                                              const float* __restrict__ dinv,
                                              const float* __restrict__ b2,
                                              const int* __restrict__ row_start,
                                              const int* __restrict__ csr_src,
                                              float* __restrict__ out) {
    int v = blockIdx.x * 8 + (threadIdx.x >> 5);
    int c = threadIdx.x & 31;
    float acc = g2[(size_t)v * 32 + c];
    int jb = row_start[v], je = row_start[v + 1];
    int j = jb;
    for (; j + 8 <= je; j += 8) {
        int i0 = csr_src[j + 0], i1 = csr_src[j + 1];
        int i2 = csr_src[j + 2], i3 = csr_src[j + 3];
        int i4 = csr_src[j + 4], i5 = csr_src[j + 5];
        int i6 = csr_src[j + 6], i7 = csr_src[j + 7];
        float a0 = g2[(size_t)i0 * 32 + c];
        float a1v = g2[(size_t)i1 * 32 + c];
        float a2 = g2[(size_t)i2 * 32 + c];
        float a3 = g2[(size_t)i3 * 32 + c];
        float a4 = g2[(size_t)i4 * 32 + c];
        float a5 = g2[(size_t)i5 * 32 + c];
        float a6 = g2[(size_t)i6 * 32 + c];
        float a7 = g2[(size_t)i7 * 32 + c];
        acc += a0 + a1v + a2 + a3 + a4 + a5 + a6 + a7;
    }
    for (; j < je; j++) {
        int s = csr_src[j];
        acc += g2[(size_t)s * 32 + c];
    }
    float z = dinv[v] * acc + b2[c];
    float m = z;
    #pragma unroll
    for (int off = 16; off >= 1; off >>= 1) m = fmaxf(m, __shfl_xor(m, off));
    float e = __expf(z - m);
    float ssum = e;
    #pragma unroll
    for (int off = 16; off >= 1; off >>= 1) ssum += __shfl_xor(ssum, off);
    out[(size_t)v * 32 + c] = (z - m) - __logf(ssum);
}

// ---------------- launch ----------------

extern "C" void kernel_launch(void* const* d_in, const int* in_sizes, int n_in,
                              void* d_out, int out_size, void* d_ws, size_t ws_size,
                              hipStream_t stream) {
    const float* x  = (const float*)d_in[0];
    const int*   ei = (const int*)d_in[1];
    const float* W1 = (const float*)d_in[2];
    const float* b1 = (const float*)d_in[3];
    const float* W2 = (const float*)d_in[4];
    const float* b2 = (const float*)d_in[5];
    float* out = (float*)d_out;

    char* ws = (char*)d_ws;
    size_t off = 0;
    auto alloc = [&](size_t bytes) {
        void* p = ws + off;
        off = (off + bytes + 255) & ~255ULL;
        return p;
    };
    // zeroed region first (single memset): flag, cnt
    int* flag = (int*)alloc(4);
    int* cnt  = (int*)alloc((size_t)NB * 4);
    size_t zero_bytes = off;
    int*   bbase     = (int*)alloc((size_t)NB * 4);
    int*   row_start = (int*)alloc((size_t)(N_NODES + 1) * 4);
    float* dinv      = (float*)alloc((size_t)N_NODES * 4);
    int*   csr_src   = (int*)alloc((size_t)N_EDGES * 4);
    ushort_t* g1     = (ushort_t*)alloc((size_t)N_NODES * 128 * 2);  // reused as g2 (f32)
    // union region: buf (pass A/B pairs, 25.09MB) then a1 (25.6MB) after k_build
    size_t ubytes = (size_t)N_NODES * 128 * 2;  // 25.6MB >= NB*CAP*8 = 25.088MB
    void* uregion = alloc(ubytes);
    uint2*    buf = (uint2*)uregion;
    ushort_t* a1  = (ushort_t*)uregion;
    float* g2 = (float*)g1;  // g1 dead after k_agg1

    hipMemsetAsync(flag, 0, zero_bytes, stream);

    k_detect<<<1, 256, 0, stream>>>(ei, flag);
    k_bucket<<<(N_EDGES + CHUNK - 1) / CHUNK, 256, 0, stream>>>(ei, flag, cnt, buf);
    k_bscan<<<1, 256, 0, stream>>>(cnt, bbase, row_start);
    k_build<<<NB, 256, 0, stream>>>(buf, cnt, bbase, row_start, dinv, csr_src);
    k_gemm1<<<(N_NODES + 63) / 64, 256, 0, stream>>>(x, W1, dinv, g1);
    k_agg1<<<N_NODES / 4, 256, 0, stream>>>(g1, dinv, b1, row_start, csr_src, a1);
    k_gemm2<<<(N_NODES + 127) / 128, 256, 0, stream>>>(a1, W2, dinv, g2);
    k_agg2<<<N_NODES / 8, 256, 0, stream>>>(g2, dinv, b2, row_start, csr_src, out);
}

// Round 5
// 214.612 us; speedup vs baseline: 2.4706x; 1.3540x over previous
//
#include <hip/hip_runtime.h>
#include <hip/hip_bf16.h>
#include <math.h>

#define N_NODES 100000
#define N_EDGES 1600000
#define NB 196        // buckets of 512 nodes: 196*512 = 100352
#define CAP 16000     // per-bucket capacity (mean 8163, sigma ~90)
#define CHUNK 4096

typedef unsigned int uint;
typedef unsigned short ushort_t;
typedef float f32x16 __attribute__((ext_vector_type(16)));
typedef __bf16 bf16x8 __attribute__((ext_vector_type(8)));

__device__ __forceinline__ float bf2f(uint h) {
    union { uint u; float f; } x; x.u = h << 16; return x.f;
}
__device__ __forceinline__ unsigned short f2bf(float f) {
    union { float f; uint u; } x; x.f = f;
    uint u = x.u;
    return (unsigned short)((u + 0x7fffu + ((u >> 16) & 1u)) >> 16);  // RNE
}
__device__ __forceinline__ bf16x8 bc8(uint4 u) { return __builtin_bit_cast(bf16x8, u); }

// ---------------- edge dtype detection ----------------
__global__ void k_detect(const int* __restrict__ ei, int* __restrict__ flag) {
    int t = threadIdx.x;
    int v = ei[2 * t + 1] | ei[2 * (t + 256) + 1];
    if (v) atomicOr(flag, 1);  // 1 => int32 layout
}

__device__ __forceinline__ int edge_at(const int* __restrict__ ei, int is32, long long idx) {
    return is32 ? ei[idx] : (int)(((const long long*)ei)[idx]);
}

// ---------------- CSR build via LDS-staged counting sort ----------------

__global__ __launch_bounds__(256) void k_bucket(const int* __restrict__ ei,
                                                const int* __restrict__ flag,
                                                int* __restrict__ cnt,
                                                uint2* __restrict__ buf) {
    __shared__ uint2 stage[CHUNK];
    __shared__ unsigned char bid[CHUNK];
    __shared__ int lcnt[256], ls[256], lbase[256], gbase[256];
    int t = threadIdx.x;
    int is32 = *flag;
    lcnt[t] = 0;
    __syncthreads();
    int base = blockIdx.x * CHUNK;
    int srcv[16], dstv[16], offv[16];
    #pragma unroll
    for (int i = 0; i < 16; i++) {
        int e = base + i * 256 + t;
        if (e < N_EDGES) {
            srcv[i] = edge_at(ei, is32, e);
            dstv[i] = edge_at(ei, is32, (long long)N_EDGES + e);
            offv[i] = atomicAdd(&lcnt[dstv[i] >> 9], 1);
        } else {
            offv[i] = -1;
        }
    }
    __syncthreads();
    int c = lcnt[t];
    ls[t] = c;
    __syncthreads();
    int val = c;
    for (int off = 1; off < 256; off <<= 1) {
        int tmp = (t >= off) ? ls[t - off] : 0;
        __syncthreads();
        val += tmp;
        ls[t] = val;
        __syncthreads();
    }
    lbase[t] = val - c;  // exclusive
    if (c > 0) gbase[t] = atomicAdd(&cnt[t], c); else gbase[t] = 0;
    __syncthreads();
    int total = ls[255];
    #pragma unroll
    for (int i = 0; i < 16; i++) {
        if (offv[i] >= 0) {
            int b = dstv[i] >> 9;
            int p = lbase[b] + offv[i];
            stage[p] = make_uint2((uint)srcv[i], (uint)dstv[i]);
            bid[p] = (unsigned char)b;
        }
    }
    __syncthreads();
    for (int idx = t; idx < total; idx += 256) {
        int b = bid[idx];
        int r = gbase[b] + (idx - lbase[b]);
        if (r < CAP) buf[(size_t)b * CAP + r] = stage[idx];
    }
}

__global__ void k_bscan(const int* __restrict__ cnt, int* __restrict__ bbase,
                        int* __restrict__ row_start) {
    __shared__ int s[256];
    int t = threadIdx.x;
    int v = (t < NB) ? cnt[t] : 0;
    s[t] = v;
    __syncthreads();
    int val = v;
    for (int off = 1; off < 256; off <<= 1) {
        int tmp = (t >= off) ? s[t - off] : 0;
        __syncthreads();
        val += tmp;
        s[t] = val;
        __syncthreads();
    }
    if (t < NB) bbase[t] = val - v;
    if (t == 0) row_start[N_NODES] = N_EDGES;
}

__global__ __launch_bounds__(256) void k_build(const uint2* __restrict__ buf,
                                               const int* __restrict__ cnt,
                                               const int* __restrict__ bbase,
                                               int* __restrict__ row_start,
                                               float* __restrict__ dinv,
                                               int* __restrict__ csr_src) {
    __shared__ int ldeg[512], lexc[512], lcur[512], s[256];
    int t = threadIdx.x;
    int b = blockIdx.x;
    int n0 = b << 9;
    int nn = min(512, N_NODES - n0);
    int ne = min(cnt[b], CAP);
    const uint2* __restrict__ in = buf + (size_t)b * CAP;
    int obase = bbase[b];
    ldeg[t] = 0; ldeg[t + 256] = 0;
    lcur[t] = 0; lcur[t + 256] = 0;
    __syncthreads();
    for (int idx = t; idx < ne; idx += 256) {
        uint2 p = in[idx];
        atomicAdd(&ldeg[p.y - n0], 1);
    }
    __syncthreads();
    int v = ldeg[2 * t] + ldeg[2 * t + 1];
    s[t] = v;
    __syncthreads();
    int val = v;
    for (int off = 1; off < 256; off <<= 1) {
        int tmp = (t >= off) ? s[t - off] : 0;
        __syncthreads();
        val += tmp;
        s[t] = val;
        __syncthreads();
    }
    int excl = val - v;
    lexc[2 * t] = excl;
    lexc[2 * t + 1] = excl + ldeg[2 * t];
    __syncthreads();
    for (int i = t; i < nn; i += 256) {
        row_start[n0 + i] = obase + lexc[i];
        dinv[n0 + i] = rsqrtf((float)(ldeg[i] + 1));  // +1 self loop
    }
    __syncthreads();
    for (int idx = t; idx < ne; idx += 256) {
        uint2 p = in[idx];
        int dl = p.y - n0;
        int pos = obase + lexc[dl] + atomicAdd(&lcur[dl], 1);
        csr_src[pos] = (int)p.x;
    }
}

// ---------------- weight prep + x cast ----------------

// wt1[c][k] = bf16(W1[k][c]) (128x128); w2t[c][k] = bf16(W2[k][c]) (32x128)
__global__ void k_prep(const float* __restrict__ W1, const float* __restrict__ W2,
                       ushort_t* __restrict__ wt1, ushort_t* __restrict__ w2t) {
    int i = blockIdx.x * 256 + threadIdx.x;
    if (i < 16384) {
        int c = i >> 7, k = i & 127;
        wt1[i] = f2bf(W1[k * 128 + c]);
    } else if (i < 20480) {
        int j = i - 16384;
        int c = j >> 7, k = j & 127;
        w2t[j] = f2bf(W2[k * 32 + c]);
    }
}

// xb = bf16(x), packed 8 elems per uint4 granule
__global__ void k_xcast(const float4* __restrict__ x, uint4* __restrict__ xb) {
    int i = blockIdx.x * blockDim.x + threadIdx.x;  // granule index
    if (i < N_NODES * 16) {
        float4 lo = x[i * 2], hi = x[i * 2 + 1];
        uint4 o;
        o.x = (uint)f2bf(lo.x) | ((uint)f2bf(lo.y) << 16);
        o.y = (uint)f2bf(lo.z) | ((uint)f2bf(lo.w) << 16);
        o.z = (uint)f2bf(hi.x) | ((uint)f2bf(hi.y) << 16);
        o.w = (uint)f2bf(hi.z) | ((uint)f2bf(hi.w) << 16);
        xb[i] = o;
    }
}

// ---------------- MFMA GEMMs ----------------
// mfma_f32_32x32x16_bf16 layouts (HW-verified, learn_hip m74/m101):
//   A: row=lane&31, k=(lane>>5)*8+j   B: col=lane&31, k=(lane>>5)*8+j
//   D: col=lane&31, row=(reg&3)+8*(reg>>2)+4*(lane>>5)

// g1 = bf16((x @ W1) * dinv[row]); block = 128 rows, wave = 32 rows x 128 cols
__global__ __launch_bounds__(256) void k_gemm1(const uint4* __restrict__ xb,
                                               const uint4* __restrict__ wt1,
                                               const float* __restrict__ dinv,
                                               ushort_t* __restrict__ g1) {
    __shared__ uint4 WT[128 * 16];
    int t = threadIdx.x;
    #pragma unroll
    for (int i = 0; i < 8; i++) {
        int gi = i * 256 + t;
        int c = gi >> 4, g = gi & 15;
        WT[c * 16 + (g ^ (c & 15))] = wt1[gi];   // swizzled store (conflict-free read)
    }
    __syncthreads();
    int w = t >> 6, l = t & 63;
    int row0 = blockIdx.x * 128 + w * 32;
    int crow = min(row0 + (l & 31), N_NODES - 1);
    int hi = l >> 5;
    f32x16 acc[4];
    #pragma unroll
    for (int ct = 0; ct < 4; ct++)
        #pragma unroll
        for (int r = 0; r < 16; r++) acc[ct][r] = 0.0f;
    const uint4* ap = xb + (size_t)crow * 16;
    #pragma unroll
    for (int k0 = 0; k0 < 8; k0++) {
        bf16x8 a = bc8(ap[k0 * 2 + hi]);
        #pragma unroll
        for (int ct = 0; ct < 4; ct++) {
            int col = ct * 32 + (l & 31);
            bf16x8 b = bc8(WT[col * 16 + ((k0 * 2 + hi) ^ (col & 15))]);
            acc[ct] = __builtin_amdgcn_mfma_f32_32x32x16_bf16(a, b, acc[ct], 0, 0, 0);
        }
    }
    #pragma unroll
    for (int reg = 0; reg < 16; reg++) {
        int row = row0 + (reg & 3) + 8 * (reg >> 2) + 4 * hi;
        if (row < N_NODES) {
            float d = dinv[row];
            #pragma unroll
            for (int ct = 0; ct < 4; ct++)
                g1[(size_t)row * 128 + ct * 32 + (l & 31)] = f2bf(acc[ct][reg] * d);
        }
    }
}

// g2 = (a1 @ W2) * dinv[row], f32 out; block = 128 rows, wave = 32 rows x 32 cols
__global__ __launch_bounds__(256) void k_gemm2(const uint4* __restrict__ a1v,
                                               const uint4* __restrict__ w2t,
                                               const float* __restrict__ dinv,
                                               float* __restrict__ g2) {
    __shared__ uint4 WT[32 * 16];
    int t = threadIdx.x;
    #pragma unroll
    for (int i = 0; i < 2; i++) {
        int gi = i * 256 + t;
        if (gi < 512) {
            int c = gi >> 4, g = gi & 15;
            WT[c * 16 + (g ^ (c & 15))] = w2t[gi];
        }
    }
    __syncthreads();
    int w = t >> 6, l = t & 63;
    int row0 = blockIdx.x * 128 + w * 32;
    int crow = min(row0 + (l & 31), N_NODES - 1);
    int hi = l >> 5;
    int col = l & 31;
    f32x16 acc;
    #pragma unroll
    for (int r = 0; r < 16; r++) acc[r] = 0.0f;
    const uint4* ap = a1v + (size_t)crow * 16;
    #pragma unroll
    for (int k0 = 0; k0 < 8; k0++) {
        bf16x8 a = bc8(ap[k0 * 2 + hi]);
        bf16x8 b = bc8(WT[col * 16 + ((k0 * 2 + hi) ^ (col & 15))]);
        acc = __builtin_amdgcn_mfma_f32_32x32x16_bf16(a, b, acc, 0, 0, 0);
    }
    #pragma unroll
    for (int reg = 0; reg < 16; reg++) {
        int row = row0 + (reg & 3) + 8 * (reg >> 2) + 4 * hi;
        if (row < N_NODES) g2[(size_t)row * 32 + col] = acc[reg] * dinv[row];
    }
}

// ---------------- aggregations ----------------

__global__ __launch_bounds__(256) void k_agg1(const ushort_t* __restrict__ g1,
                                              const float* __restrict__ dinv,
                                              const float* __restrict__ b1,
                                              const int* __restrict__ row_start,
                                              const int* __restrict__ csr_src,
                                              ushort_t* __restrict__ a1) {
    int v = blockIdx.x * 4 + (threadIdx.x >> 6);
    int col = threadIdx.x & 63;
    const uint* __restrict__ g = (const uint*)g1;
    uint w = g[(size_t)v * 64 + col];
    float s0 = bf2f(w & 0xffffu), s1 = bf2f(w >> 16);
    int jb = row_start[v], je = row_start[v + 1];
    int j = jb;
    for (; j + 8 <= je; j += 8) {
        int i0 = csr_src[j + 0], i1 = csr_src[j + 1];
        int i2 = csr_src[j + 2], i3 = csr_src[j + 3];
        int i4 = csr_src[j + 4], i5 = csr_src[j + 5];
        int i6 = csr_src[j + 6], i7 = csr_src[j + 7];
        uint u0 = g[(size_t)i0 * 64 + col];
        uint u1 = g[(size_t)i1 * 64 + col];
        uint u2 = g[(size_t)i2 * 64 + col];
        uint u3 = g[(size_t)i3 * 64 + col];
        uint u4 = g[(size_t)i4 * 64 + col];
        uint u5 = g[(size_t)i5 * 64 + col];
        uint u6 = g[(size_t)i6 * 64 + col];
        uint u7 = g[(size_t)i7 * 64 + col];
        s0 += bf2f(u0 & 0xffffu) + bf2f(u1 & 0xffffu) + bf2f(u2 & 0xffffu) + bf2f(u3 & 0xffffu)
            + bf2f(u4 & 0xffffu) + bf2f(u5 & 0xffffu) + bf2f(u6 & 0xffffu) + bf2f(u7 & 0xffffu);
        s1 += bf2f(u0 >> 16) + bf2f(u1 >> 16) + bf2f(u2 >> 16) + bf2f(u3 >> 16)
            + bf2f(u4 >> 16) + bf2f(u5 >> 16) + bf2f(u6 >> 16) + bf2f(u7 >> 16);
    }
    for (; j < je; j++) {
        int s = csr_src[j];
        uint u = g[(size_t)s * 64 + col];
        s0 += bf2f(u & 0xffffu);
        s1 += bf2f(u >> 16);
    }
    int c2 = col * 2;
    float d = dinv[v];
    float o0 = fmaxf(d * s0 + b1[c2], 0.0f);
    float o1 = fmaxf(d * s1 + b1[c2 + 1], 0.0f);
    uint ow = (uint)f2bf(o0) | ((uint)f2bf(o1) << 16);
    *(uint*)(a1 + (size_t)v * 128 + c2) = ow;
}

__global__ __launch_bounds__(256) void k_agg2(const float* __restrict__ g2,
                                              const float* __restrict__ dinv,
                                              const float* __restrict__ b2,
                                              const int* __restrict__ row_start,
                                              const int* __restrict__ csr_src,
                                              float* __restrict__ out) {
    int v = blockIdx.x * 8 + (threadIdx.x >> 5);
    int c = threadIdx.x & 31;
    float acc = g2[(size_t)v * 32 + c];
    int jb = row_start[v], je = row_start[v + 1];
    int j = jb;
    for (; j + 8 <= je; j += 8) {
        int i0 = csr_src[j + 0], i1 = csr_src[j + 1];
        int i2 = csr_src[j + 2], i3 = csr_src[j + 3];
        int i4 = csr_src[j + 4], i5 = csr_src[j + 5];
        int i6 = csr_src[j + 6], i7 = csr_src[j + 7];
        float a0 = g2[(size_t)i0 * 32 + c];
        float a1v = g2[(size_t)i1 * 32 + c];
        float a2 = g2[(size_t)i2 * 32 + c];
        float a3 = g2[(size_t)i3 * 32 + c];
        float a4 = g2[(size_t)i4 * 32 + c];
        float a5 = g2[(size_t)i5 * 32 + c];
        float a6 = g2[(size_t)i6 * 32 + c];
        float a7 = g2[(size_t)i7 * 32 + c];
        acc += a0 + a1v + a2 + a3 + a4 + a5 + a6 + a7;
    }
    for (; j < je; j++) {
        int s = csr_src[j];
        acc += g2[(size_t)s * 32 + c];
    }
    float z = dinv[v] * acc + b2[c];
    float m = z;
    #pragma unroll
    for (int off = 16; off >= 1; off >>= 1) m = fmaxf(m, __shfl_xor(m, off));
    float e = __expf(z - m);
    float ssum = e;
    #pragma unroll
    for (int off = 16; off >= 1; off >>= 1) ssum += __shfl_xor(ssum, off);
    out[(size_t)v * 32 + c] = (z - m) - __logf(ssum);
}

// ---------------- launch ----------------

extern "C" void kernel_launch(void* const* d_in, const int* in_sizes, int n_in,
                              void* d_out, int out_size, void* d_ws, size_t ws_size,
                              hipStream_t stream) {
    const float* x  = (const float*)d_in[0];
    const int*   ei = (const int*)d_in[1];
    const float* W1 = (const float*)d_in[2];
    const float* b1 = (const float*)d_in[3];
    const float* W2 = (const float*)d_in[4];
    const float* b2 = (const float*)d_in[5];
    float* out = (float*)d_out;

    char* ws = (char*)d_ws;
    size_t off = 0;
    auto alloc = [&](size_t bytes) {
        void* p = ws + off;
        off = (off + bytes + 255) & ~255ULL;
        return p;
    };
    // zeroed region first (single memset): flag, cnt
    int* flag = (int*)alloc(4);
    int* cnt  = (int*)alloc((size_t)NB * 4);
    size_t zero_bytes = off;
    int*   bbase     = (int*)alloc((size_t)NB * 4);
    int*   row_start = (int*)alloc((size_t)(N_NODES + 1) * 4);
    float* dinv      = (float*)alloc((size_t)N_NODES * 4);
    int*   csr_src   = (int*)alloc((size_t)N_EDGES * 4);
    ushort_t* wt1g   = (ushort_t*)alloc(16384 * 2);
    ushort_t* w2tg   = (ushort_t*)alloc(4096 * 2);
    ushort_t* g1     = (ushort_t*)alloc((size_t)N_NODES * 128 * 2);  // reused as g2 (f32)
    // union region (25.6MB): buf (CSR pairs) -> xb (bf16 x) -> a1 (bf16 acts)
    // lifetimes: buf [bucket,build], xb [xcast,gemm1], a1 [agg1,gemm2] - disjoint
    size_t ubytes = (size_t)N_NODES * 128 * 2;  // >= NB*CAP*8 = 25.088MB
    void* uregion = alloc(ubytes);
    uint2*    buf = (uint2*)uregion;
    uint4*    xb  = (uint4*)uregion;
    ushort_t* a1  = (ushort_t*)uregion;
    float* g2 = (float*)g1;  // g1 dead after k_agg1

    hipMemsetAsync(flag, 0, zero_bytes, stream);

    k_detect<<<1, 256, 0, stream>>>(ei, flag);
    k_bucket<<<(N_EDGES + CHUNK - 1) / CHUNK, 256, 0, stream>>>(ei, flag, cnt, buf);
    k_bscan<<<1, 256, 0, stream>>>(cnt, bbase, row_start);
    k_build<<<NB, 256, 0, stream>>>(buf, cnt, bbase, row_start, dinv, csr_src);
    k_prep<<<80, 256, 0, stream>>>(W1, W2, wt1g, w2tg);
    k_xcast<<<(N_NODES * 16 + 255) / 256, 256, 0, stream>>>((const float4*)x, xb);
    k_gemm1<<<(N_NODES + 127) / 128, 256, 0, stream>>>(xb, (const uint4*)wt1g, dinv, g1);
    k_agg1<<<N_NODES / 4, 256, 0, stream>>>(g1, dinv, b1, row_start, csr_src, a1);
    k_gemm2<<<(N_NODES + 127) / 128, 256, 0, stream>>>((const uint4*)a1, (const uint4*)w2tg, dinv, g2);
    k_agg2<<<N_NODES / 8, 256, 0, stream>>>(g2, dinv, b2, row_start, csr_src, out);
}

// Round 7
// 174.398 us; speedup vs baseline: 3.0402x; 1.2306x over previous
//
#include <hip/hip_runtime.h>
#include <hip/hip_bf16.h>
#include <math.h>

#define N_NODES 100000
#define N_EDGES 1600000
#define NB 196        // buckets of 512 nodes
#define CAP 16000     // per-bucket capacity (mean 8163)
#define CHUNK 4096

typedef unsigned int uint;
typedef unsigned short ushort_t;
typedef float f32x16 __attribute__((ext_vector_type(16)));
typedef float f32x2 __attribute__((ext_vector_type(2)));
typedef __bf16 bf16x8 __attribute__((ext_vector_type(8)));

__device__ __forceinline__ float bf2f(uint h) {
    union { uint u; float f; } x; x.u = h << 16; return x.f;
}
__device__ __forceinline__ unsigned short f2bf(float f) {
    union { float f; uint u; } x; x.f = f;
    uint u = x.u;
    return (unsigned short)((u + 0x7fffu + ((u >> 16) & 1u)) >> 16);  // RNE
}
__device__ __forceinline__ uint pk2(float a, float b) {
    return (uint)f2bf(a) | ((uint)f2bf(b) << 16);
}
__device__ __forceinline__ bf16x8 bc8(uint4 u) { return __builtin_bit_cast(bf16x8, u); }

// ---------------- edge dtype detection ----------------
__global__ void k_detect(const int* __restrict__ ei, int* __restrict__ flag) {
    int t = threadIdx.x;
    int v = ei[2 * t + 1] | ei[2 * (t + 256) + 1];
    if (v) atomicOr(flag, 1);  // 1 => int32 layout
}

__device__ __forceinline__ int edge_at(const int* __restrict__ ei, int is32, long long idx) {
    return is32 ? ei[idx] : (int)(((const long long*)ei)[idx]);
}

// ---------------- CSR build via LDS-staged counting sort ----------------
// buf entry: src (17b) | dst_local (9b) << 17

__global__ __launch_bounds__(256) void k_bucket(const int* __restrict__ ei,
                                                const int* __restrict__ flag,
                                                int* __restrict__ cnt,
                                                uint* __restrict__ buf) {
    __shared__ uint stage[CHUNK];
    __shared__ unsigned char bid[CHUNK];
    __shared__ int lcnt[256], ls[256], lbase[256], gbase[256];
    int t = threadIdx.x;
    int is32 = *flag;
    lcnt[t] = 0;
    __syncthreads();
    int base = blockIdx.x * CHUNK;
    int srcv[16], dstv[16], offv[16];
    #pragma unroll
    for (int i = 0; i < 16; i++) {
        int e = base + i * 256 + t;
        if (e < N_EDGES) {
            srcv[i] = edge_at(ei, is32, e);
            dstv[i] = edge_at(ei, is32, (long long)N_EDGES + e);
            offv[i] = atomicAdd(&lcnt[dstv[i] >> 9], 1);
        } else {
            offv[i] = -1;
        }
    }
    __syncthreads();
    int c = lcnt[t];
    ls[t] = c;
    __syncthreads();
    int val = c;
    for (int off = 1; off < 256; off <<= 1) {
        int tmp = (t >= off) ? ls[t - off] : 0;
        __syncthreads();
        val += tmp;
        ls[t] = val;
        __syncthreads();
    }
    lbase[t] = val - c;  // exclusive
    if (c > 0) gbase[t] = atomicAdd(&cnt[t], c); else gbase[t] = 0;
    __syncthreads();
    int total = ls[255];
    #pragma unroll
    for (int i = 0; i < 16; i++) {
        if (offv[i] >= 0) {
            int b = dstv[i] >> 9;
            int p = lbase[b] + offv[i];
            stage[p] = (uint)srcv[i] | ((uint)(dstv[i] & 511) << 17);
            bid[p] = (unsigned char)b;
        }
    }
    __syncthreads();
    for (int idx = t; idx < total; idx += 256) {
        int b = bid[idx];
        int r = gbase[b] + (idx - lbase[b]);
        if (r < CAP) buf[(size_t)b * CAP + r] = stage[idx];
    }
}

__global__ void k_bscan(const int* __restrict__ cnt, int* __restrict__ bbase,
                        int* __restrict__ row_start) {
    __shared__ int s[256];
    int t = threadIdx.x;
    int v = (t < NB) ? cnt[t] : 0;
    s[t] = v;
    __syncthreads();
    int val = v;
    for (int off = 1; off < 256; off <<= 1) {
        int tmp = (t >= off) ? s[t - off] : 0;
        __syncthreads();
        val += tmp;
        s[t] = val;
        __syncthreads();
    }
    if (t < NB) bbase[t] = val - v;
    if (t == 0) row_start[N_NODES] = N_EDGES;
}

__global__ __launch_bounds__(256) void k_build(const uint* __restrict__ buf,
                                               const int* __restrict__ cnt,
                                               const int* __restrict__ bbase,
                                               int* __restrict__ row_start,
                                               float* __restrict__ dinv,
                                               int* __restrict__ csr_src) {
    __shared__ int ldeg[512], lexc[512], lcur[512], s[256];
    int t = threadIdx.x;
    int b = blockIdx.x;
    int n0 = b << 9;
    int nn = min(512, N_NODES - n0);
    int ne = min(cnt[b], CAP);
    const uint* __restrict__ in = buf + (size_t)b * CAP;
    int obase = bbase[b];
    ldeg[t] = 0; ldeg[t + 256] = 0;
    lcur[t] = 0; lcur[t + 256] = 0;
    __syncthreads();
    for (int idx = t; idx < ne; idx += 256) {
        atomicAdd(&ldeg[in[idx] >> 17], 1);
    }
    __syncthreads();
    int v = ldeg[2 * t] + ldeg[2 * t + 1];
    s[t] = v;
    __syncthreads();
    int val = v;
    for (int off = 1; off < 256; off <<= 1) {
        int tmp = (t >= off) ? s[t - off] : 0;
        __syncthreads();
        val += tmp;
        s[t] = val;
        __syncthreads();
    }
    int excl = val - v;
    lexc[2 * t] = excl;
    lexc[2 * t + 1] = excl + ldeg[2 * t];
    __syncthreads();
    for (int i = t; i < nn; i += 256) {
        row_start[n0 + i] = obase + lexc[i];
        dinv[n0 + i] = rsqrtf((float)(ldeg[i] + 1));  // +1 self loop
    }
    __syncthreads();
    for (int idx = t; idx < ne; idx += 256) {
        uint p = in[idx];
        int dl = p >> 17;
        int pos = obase + lexc[dl] + atomicAdd(&lcur[dl], 1);
        csr_src[pos] = (int)(p & 0x1FFFFu);
    }
}

// ---------------- weight prep ----------------
// wt1[c][k] = bf16(W1[k][c])  (logical col-major, 128x128)
// w2t[c][p] = bf16(W2[cl(p)][c]) where cl(p) = (p&3)*32 + (p>>2)  (phys-k-permuted)
__global__ void k_prep(const float* __restrict__ W1, const float* __restrict__ W2,
                       ushort_t* __restrict__ wt1, ushort_t* __restrict__ w2t) {
    int i = blockIdx.x * 256 + threadIdx.x;
    if (i < 16384) {
        int c = i >> 7, k = i & 127;
        wt1[i] = f2bf(W1[k * 128 + c]);
    } else if (i < 20480) {
        int j = i - 16384;
        int c = j >> 7, p = j & 127;
        int cl = (p & 3) * 32 + (p >> 2);
        w2t[j] = f2bf(W2[cl * 32 + c]);
    }
}

// ---------------- MFMA GEMMs ----------------
// mfma_f32_32x32x16_bf16: A row=lane&31,k=(lane>>5)*8+j; B col=lane&31,same k;
// D col=lane&31, row=(reg&3)+8*(reg>>2)+4*(lane>>5)

// g1p = fp8((x @ W1) * dinv[row]), physically col-permuted: phys p=(l&31)*4+ct
__global__ __launch_bounds__(256) void k_gemm1(const float4* __restrict__ xf,
                                               const uint4* __restrict__ wt1,
                                               const float* __restrict__ dinv,
                                               uint* __restrict__ g1p) {
    __shared__ uint4 WT[128 * 16];
    int t = threadIdx.x;
    #pragma unroll
    for (int i = 0; i < 8; i++) {
        int gi = i * 256 + t;
        int c = gi >> 4, g = gi & 15;
        WT[c * 16 + (g ^ (c & 15))] = wt1[gi];   // swizzled store (conflict-free read)
    }
    __syncthreads();
    int w = t >> 6, l = t & 63;
    int row0 = blockIdx.x * 128 + w * 32;
    int crow = min(row0 + (l & 31), N_NODES - 1);
    int hi = l >> 5;
    f32x16 acc[4];
    #pragma unroll
    for (int ct = 0; ct < 4; ct++)
        #pragma unroll
        for (int r = 0; r < 16; r++) acc[ct][r] = 0.0f;
    const float4* ap = xf + (size_t)crow * 32;
    #pragma unroll
    for (int k0 = 0; k0 < 8; k0++) {
        float4 f0 = ap[(k0 * 2 + hi) * 2];
        float4 f1 = ap[(k0 * 2 + hi) * 2 + 1];
        uint4 au;
        au.x = pk2(f0.x, f0.y); au.y = pk2(f0.z, f0.w);
        au.z = pk2(f1.x, f1.y); au.w = pk2(f1.z, f1.w);
        bf16x8 a = bc8(au);
        #pragma unroll
        for (int ct = 0; ct < 4; ct++) {
            int col = ct * 32 + (l & 31);
            bf16x8 b = bc8(WT[col * 16 + ((k0 * 2 + hi) ^ (col & 15))]);
            acc[ct] = __builtin_amdgcn_mfma_f32_32x32x16_bf16(a, b, acc[ct], 0, 0, 0);
        }
    }
    #pragma unroll
    for (int reg = 0; reg < 16; reg++) {
        int row = row0 + (reg & 3) + 8 * (reg >> 2) + 4 * hi;
        if (row < N_NODES) {
            float d = dinv[row];
            int pw = __builtin_amdgcn_cvt_pk_fp8_f32(acc[0][reg] * d, acc[1][reg] * d, 0, false);
            pw = __builtin_amdgcn_cvt_pk_fp8_f32(acc[2][reg] * d, acc[3][reg] * d, pw, true);
            g1p[(size_t)row * 32 + (l & 31)] = (uint)pw;
        }
    }
}

// g2b = bf16((a1 @ W2) * dinv[row]); a1 phys-layout bf16, w2t phys-permuted
__global__ __launch_bounds__(256) void k_gemm2(const uint4* __restrict__ a1v,
                                               const uint4* __restrict__ w2t,
                                               const float* __restrict__ dinv,
                                               ushort_t* __restrict__ g2b) {
    __shared__ uint4 WT[32 * 16];
    int t = threadIdx.x;
    #pragma unroll
    for (int i = 0; i < 2; i++) {
        int gi = i * 256 + t;
        int c = gi >> 4, g = gi & 15;
        WT[c * 16 + (g ^ (c & 15))] = w2t[gi];
    }
    __syncthreads();
    int w = t >> 6, l = t & 63;
    int row0 = blockIdx.x * 128 + w * 32;
    int crow = min(row0 + (l & 31), N_NODES - 1);
    int hi = l >> 5;
    int col = l & 31;
    f32x16 acc;
    #pragma unroll
    for (int r = 0; r < 16; r++) acc[r] = 0.0f;
    const uint4* ap = a1v + (size_t)crow * 16;
    #pragma unroll
    for (int k0 = 0; k0 < 8; k0++) {
        bf16x8 a = bc8(ap[k0 * 2 + hi]);
        bf16x8 b = bc8(WT[col * 16 + ((k0 * 2 + hi) ^ (col & 15))]);
        acc = __builtin_amdgcn_mfma_f32_32x32x16_bf16(a, b, acc, 0, 0, 0);
    }
    #pragma unroll
    for (int reg = 0; reg < 16; reg++) {
        int row = row0 + (reg & 3) + 8 * (reg >> 2) + 4 * hi;
        if (row < N_NODES) g2b[(size_t)row * 32 + col] = f2bf(acc[reg] * dinv[row]);
    }
}

// ---------------- aggregations ----------------

// a1[v] = bf16(relu(dinv[v]*(g1[v] + sum g1[s]) + b1)), phys col layout.
// 32 lanes per node: lane L covers phys cols 4L..4L+3 (one uint of fp8).
__global__ __launch_bounds__(256) void k_agg1(const uint* __restrict__ g1p,
                                              const float* __restrict__ dinv,
                                              const float* __restrict__ b1,
                                              const int* __restrict__ row_start,
                                              const int* __restrict__ csr_src,
                                              uint2* __restrict__ a1) {
    int v = blockIdx.x * 8 + (threadIdx.x >> 5);
    int L = threadIdx.x & 31;
    uint u = g1p[(size_t)v * 32 + L];
    f32x2 lo = __builtin_amdgcn_cvt_pk_f32_fp8(u, false);
    f32x2 hh = __builtin_amdgcn_cvt_pk_f32_fp8(u, true);
    float s0 = lo[0], s1 = lo[1], s2 = hh[0], s3 = hh[1];
    int jb = row_start[v], je = row_start[v + 1];
    int j = jb;
    for (; j + 8 <= je; j += 8) {
        int i0 = csr_src[j + 0], i1 = csr_src[j + 1];
        int i2 = csr_src[j + 2], i3 = csr_src[j + 3];
        int i4 = csr_src[j + 4], i5 = csr_src[j + 5];
        int i6 = csr_src[j + 6], i7 = csr_src[j + 7];
        uint u0 = g1p[(size_t)i0 * 32 + L];
        uint u1 = g1p[(size_t)i1 * 32 + L];
        uint u2 = g1p[(size_t)i2 * 32 + L];
        uint u3 = g1p[(size_t)i3 * 32 + L];
        uint u4 = g1p[(size_t)i4 * 32 + L];
        uint u5 = g1p[(size_t)i5 * 32 + L];
        uint u6 = g1p[(size_t)i6 * 32 + L];
        uint u7 = g1p[(size_t)i7 * 32 + L];
        #pragma unroll
        for (int q = 0; q < 8; q++) {
            uint uu = q == 0 ? u0 : q == 1 ? u1 : q == 2 ? u2 : q == 3 ? u3
                    : q == 4 ? u4 : q == 5 ? u5 : q == 6 ? u6 : u7;
            f32x2 a = __builtin_amdgcn_cvt_pk_f32_fp8(uu, false);
            f32x2 bfv = __builtin_amdgcn_cvt_pk_f32_fp8(uu, true);
            s0 += a[0]; s1 += a[1]; s2 += bfv[0]; s3 += bfv[1];
        }
    }
    for (; j < je; j++) {
        uint uu = g1p[(size_t)csr_src[j] * 32 + L];
        f32x2 a = __builtin_amdgcn_cvt_pk_f32_fp8(uu, false);
        f32x2 bfv = __builtin_amdgcn_cvt_pk_f32_fp8(uu, true);
        s0 += a[0]; s1 += a[1]; s2 += bfv[0]; s3 += bfv[1];
    }
    float d = dinv[v];
    // phys p = 4L+q -> logical c = q*32 + L
    float o0 = fmaxf(d * s0 + b1[L], 0.0f);
    float o1 = fmaxf(d * s1 + b1[32 + L], 0.0f);
    float o2 = fmaxf(d * s2 + b1[64 + L], 0.0f);
    float o3 = fmaxf(d * s3 + b1[96 + L], 0.0f);
    uint2 ow;
    ow.x = pk2(o0, o1);
    ow.y = pk2(o2, o3);
    a1[(size_t)v * 32 + L] = ow;
}

// out[v] = log_softmax(dinv[v]*(g2[v] + sum g2[s]) + b2); g2 bf16
__global__ __launch_bounds__(256) void k_agg2(const ushort_t* __restrict__ g2b,
                                              const float* __restrict__ dinv,
                                              const float* __restrict__ b2,
                                              const int* __restrict__ row_start,
                                              const int* __restrict__ csr_src,
                                              float* __restrict__ out) {
    int v = blockIdx.x * 8 + (threadIdx.x >> 5);
    int c = threadIdx.x & 31;
    float acc = bf2f(g2b[(size_t)v * 32 + c]);
    int jb = row_start[v], je = row_start[v + 1];
    int j = jb;
    for (; j + 8 <= je; j += 8) {
        int i0 = csr_src[j + 0], i1 = csr_src[j + 1];
        int i2 = csr_src[j + 2], i3 = csr_src[j + 3];
        int i4 = csr_src[j + 4], i5 = csr_src[j + 5];
        int i6 = csr_src[j + 6], i7 = csr_src[j + 7];
        uint a0 = g2b[(size_t)i0 * 32 + c];
        uint a1v = g2b[(size_t)i1 * 32 + c];
        uint a2 = g2b[(size_t)i2 * 32 + c];
        uint a3 = g2b[(size_t)i3 * 32 + c];
        uint a4 = g2b[(size_t)i4 * 32 + c];
        uint a5 = g2b[(size_t)i5 * 32 + c];
        uint a6 = g2b[(size_t)i6 * 32 + c];
        uint a7 = g2b[(size_t)i7 * 32 + c];
        acc += bf2f(a0) + bf2f(a1v) + bf2f(a2) + bf2f(a3)
             + bf2f(a4) + bf2f(a5) + bf2f(a6) + bf2f(a7);
    }
    for (; j < je; j++) {
        acc += bf2f(g2b[(size_t)csr_src[j] * 32 + c]);
    }
    float z = dinv[v] * acc + b2[c];
    float m = z;
    #pragma unroll
    for (int off = 16; off >= 1; off >>= 1) m = fmaxf(m, __shfl_xor(m, off));
    float e = __expf(z - m);
    float ssum = e;
    #pragma unroll
    for (int off = 16; off >= 1; off >>= 1) ssum += __shfl_xor(ssum, off);
    out[(size_t)v * 32 + c] = (z - m) - __logf(ssum);
}

// ---------------- launch ----------------

extern "C" void kernel_launch(void* const* d_in, const int* in_sizes, int n_in,
                              void* d_out, int out_size, void* d_ws, size_t ws_size,
                              hipStream_t stream) {
    const float* x  = (const float*)d_in[0];
    const int*   ei = (const int*)d_in[1];
    const float* W1 = (const float*)d_in[2];
    const float* b1 = (const float*)d_in[3];
    const float* W2 = (const float*)d_in[4];
    const float* b2 = (const float*)d_in[5];
    float* out = (float*)d_out;

    char* ws = (char*)d_ws;
    size_t off = 0;
    auto alloc = [&](size_t bytes) {
        void* p = ws + off;
        off = (off + bytes + 255) & ~255ULL;
        return p;
    };
    // zeroed region first (single memset): flag, cnt
    int* flag = (int*)alloc(4);
    int* cnt  = (int*)alloc((size_t)NB * 4);
    size_t zero_bytes = off;
    int*   bbase     = (int*)alloc((size_t)NB * 4);
    int*   row_start = (int*)alloc((size_t)(N_NODES + 1) * 4);
    float* dinv      = (float*)alloc((size_t)N_NODES * 4);
    int*   csr_src   = (int*)alloc((size_t)N_EDGES * 4);
    ushort_t* wt1g   = (ushort_t*)alloc(16384 * 2);
    ushort_t* w2tg   = (ushort_t*)alloc(4096 * 2);
    uint*  g1p       = (uint*)alloc((size_t)N_NODES * 128);      // fp8, reused as g2b (bf16 6.4MB)
    // union region: buf (uint pairs, 12.5MB) -> a1 (bf16 25.6MB); disjoint lifetimes
    size_t ubytes = (size_t)N_NODES * 128 * 2;
    void* uregion = alloc(ubytes);
    uint*  buf = (uint*)uregion;
    uint2* a1  = (uint2*)uregion;
    ushort_t* g2b = (ushort_t*)g1p;  // g1p dead after k_agg1

    hipMemsetAsync(flag, 0, zero_bytes, stream);

    k_detect<<<1, 256, 0, stream>>>(ei, flag);
    k_bucket<<<(N_EDGES + CHUNK - 1) / CHUNK, 256, 0, stream>>>(ei, flag, cnt, buf);
    k_bscan<<<1, 256, 0, stream>>>(cnt, bbase, row_start);
    k_build<<<NB, 256, 0, stream>>>(buf, cnt, bbase, row_start, dinv, csr_src);
    k_prep<<<80, 256, 0, stream>>>(W1, W2, wt1g, w2tg);
    k_gemm1<<<(N_NODES + 127) / 128, 256, 0, stream>>>((const float4*)x, (const uint4*)wt1g, dinv, g1p);
    k_agg1<<<N_NODES / 8, 256, 0, stream>>>(g1p, dinv, b1, row_start, csr_src, a1);
    k_gemm2<<<(N_NODES + 127) / 128, 256, 0, stream>>>((const uint4*)a1, (const uint4*)w2tg, dinv, g2b);
    k_agg2<<<N_NODES / 8, 256, 0, stream>>>(g2b, dinv, b2, row_start, csr_src, out);
}

// Round 8
// 157.206 us; speedup vs baseline: 3.3727x; 1.1094x over previous
//
#include <hip/hip_runtime.h>
#include <hip/hip_bf16.h>
#include <math.h>

#define N_NODES 100000
#define N_EDGES 1600000
#define NB 196        // buckets of 512 nodes
#define CAP 16000     // per-bucket capacity (mean 8163)
#define CHUNK 4096

typedef unsigned int uint;
typedef unsigned short ushort_t;
typedef float f32x16 __attribute__((ext_vector_type(16)));
typedef float f32x2 __attribute__((ext_vector_type(2)));
typedef __bf16 bf16x8 __attribute__((ext_vector_type(8)));

__device__ __forceinline__ float bf2f(uint h) {
    union { uint u; float f; } x; x.u = h << 16; return x.f;
}
__device__ __forceinline__ unsigned short f2bf(float f) {
    union { float f; uint u; } x; x.f = f;
    uint u = x.u;
    return (unsigned short)((u + 0x7fffu + ((u >> 16) & 1u)) >> 16);  // RNE
}
__device__ __forceinline__ uint pk2(float a, float b) {
    return (uint)f2bf(a) | ((uint)f2bf(b) << 16);
}
__device__ __forceinline__ bf16x8 bc8(uint4 u) { return __builtin_bit_cast(bf16x8, u); }

__device__ __forceinline__ int edge_at(const int* __restrict__ ei, int is32, long long idx) {
    return is32 ? ei[idx] : (int)(((const long long*)ei)[idx]);
}

// ---------------- CSR build via LDS-staged counting sort ----------------
// buf entry: src (17b) | dst_local (9b) << 17

__global__ __launch_bounds__(256) void k_bucket(const int* __restrict__ ei,
                                                const int* __restrict__ flag,
                                                int* __restrict__ cnt,
                                                uint* __restrict__ buf) {
    __shared__ uint stage[CHUNK];
    __shared__ unsigned char bid[CHUNK];
    __shared__ int lcnt[256], ls[256], lbase[256], gbase[256];
    int t = threadIdx.x;
    int is32 = *flag;
    lcnt[t] = 0;
    __syncthreads();
    int base = blockIdx.x * CHUNK;
    int srcv[16], dstv[16], offv[16];
    #pragma unroll
    for (int i = 0; i < 16; i++) {
        int e = base + i * 256 + t;
        if (e < N_EDGES) {
            srcv[i] = edge_at(ei, is32, e);
            dstv[i] = edge_at(ei, is32, (long long)N_EDGES + e);
            offv[i] = atomicAdd(&lcnt[dstv[i] >> 9], 1);
        } else {
            offv[i] = -1;
        }
    }
    __syncthreads();
    int c = lcnt[t];
    ls[t] = c;
    __syncthreads();
    int val = c;
    for (int off = 1; off < 256; off <<= 1) {
        int tmp = (t >= off) ? ls[t - off] : 0;
        __syncthreads();
        val += tmp;
        ls[t] = val;
        __syncthreads();
    }
    lbase[t] = val - c;  // exclusive
    if (c > 0) gbase[t] = atomicAdd(&cnt[t], c); else gbase[t] = 0;
    __syncthreads();
    int total = ls[255];
    #pragma unroll
    for (int i = 0; i < 16; i++) {
        if (offv[i] >= 0) {
            int b = dstv[i] >> 9;
            int p = lbase[b] + offv[i];
            stage[p] = (uint)srcv[i] | ((uint)(dstv[i] & 511) << 17);
            bid[p] = (unsigned char)b;
        }
    }
    __syncthreads();
    for (int idx = t; idx < total; idx += 256) {
        int b = bid[idx];
        int r = gbase[b] + (idx - lbase[b]);
        if (r < CAP) buf[(size_t)b * CAP + r] = stage[idx];
    }
}

__global__ void k_bscan(const int* __restrict__ cnt, int* __restrict__ bbase,
                        int* __restrict__ row_start) {
    __shared__ int s[256];
    int t = threadIdx.x;
    int v = (t < NB) ? cnt[t] : 0;
    s[t] = v;
    __syncthreads();
    int val = v;
    for (int off = 1; off < 256; off <<= 1) {
        int tmp = (t >= off) ? s[t - off] : 0;
        __syncthreads();
        val += tmp;
        s[t] = val;
        __syncthreads();
    }
    if (t < NB) bbase[t] = val - v;
    if (t == 0) row_start[N_NODES] = N_EDGES;
}

__global__ __launch_bounds__(256) void k_build(const uint* __restrict__ buf,
                                               const int* __restrict__ cnt,
                                               const int* __restrict__ bbase,
                                               int* __restrict__ row_start,
                                               float* __restrict__ dinv,
                                               int* __restrict__ csr_src) {
    __shared__ int ldeg[512], lexc[512], lcur[512], s[256];
    int t = threadIdx.x;
    int b = blockIdx.x;
    int n0 = b << 9;
    int nn = min(512, N_NODES - n0);
    int ne = min(cnt[b], CAP);
    const uint* __restrict__ in = buf + (size_t)b * CAP;
    int obase = bbase[b];
    ldeg[t] = 0; ldeg[t + 256] = 0;
    lcur[t] = 0; lcur[t + 256] = 0;
    __syncthreads();
    for (int idx = t; idx < ne; idx += 256) {
        atomicAdd(&ldeg[in[idx] >> 17], 1);
    }
    __syncthreads();
    int v = ldeg[2 * t] + ldeg[2 * t + 1];
    s[t] = v;
    __syncthreads();
    int val = v;
    for (int off = 1; off < 256; off <<= 1) {
        int tmp = (t >= off) ? s[t - off] : 0;
        __syncthreads();
        val += tmp;
        s[t] = val;
        __syncthreads();
    }
    int excl = val - v;
    lexc[2 * t] = excl;
    lexc[2 * t + 1] = excl + ldeg[2 * t];
    __syncthreads();
    for (int i = t; i < nn; i += 256) {
        row_start[n0 + i] = obase + lexc[i];
        dinv[n0 + i] = rsqrtf((float)(ldeg[i] + 1));  // +1 self loop
    }
    __syncthreads();
    for (int idx = t; idx < ne; idx += 256) {
        uint p = in[idx];
        int dl = p >> 17;
        int pos = obase + lexc[dl] + atomicAdd(&lcur[dl], 1);
        csr_src[pos] = (int)(p & 0x1FFFFu);
    }
}

// ---------------- weight prep (+ edge dtype detect in block 0) ----------------
// wt1[c][k] = bf16(W1[k][c]); w2t[c][p] = bf16(W2[cl(p)][c]), cl(p)=(p&3)*32+(p>>2)
__global__ void k_prep(const float* __restrict__ W1, const float* __restrict__ W2,
                       ushort_t* __restrict__ wt1, ushort_t* __restrict__ w2t,
                       const int* __restrict__ ei, int* __restrict__ flag) {
    int t = threadIdx.x;
    if (blockIdx.x == 0) {
        int v = ei[2 * t + 1] | ei[2 * (t + 256) + 1];
        if (v) atomicOr(flag, 1);  // 1 => int32 layout
    }
    int i = blockIdx.x * 256 + t;
    if (i < 16384) {
        int c = i >> 7, k = i & 127;
        wt1[i] = f2bf(W1[k * 128 + c]);
    } else if (i < 20480) {
        int j = i - 16384;
        int c = j >> 7, p = j & 127;
        int cl = (p & 3) * 32 + (p >> 2);
        w2t[j] = f2bf(W2[cl * 32 + c]);
    }
}

// ---------------- MFMA GEMMs ----------------
// mfma_f32_32x32x16_bf16: A row=lane&31,k=(lane>>5)*8+j; B col=lane&31,same k;
// D col=lane&31, row=(reg&3)+8*(reg>>2)+4*(lane>>5)

// g1p = fp8((x @ W1) * dinv[row]), physically col-permuted: phys p=(l&31)*4+ct
__global__ __launch_bounds__(256) void k_gemm1(const float4* __restrict__ xf,
                                               const uint4* __restrict__ wt1,
                                               const float* __restrict__ dinv,
                                               uint* __restrict__ g1p) {
    __shared__ uint4 WT[128 * 16];
    int t = threadIdx.x;
    #pragma unroll
    for (int i = 0; i < 8; i++) {
        int gi = i * 256 + t;
        int c = gi >> 4, g = gi & 15;
        WT[c * 16 + (g ^ (c & 15))] = wt1[gi];   // swizzled store (conflict-free read)
    }
    __syncthreads();
    int w = t >> 6, l = t & 63;
    int row0 = blockIdx.x * 128 + w * 32;
    int crow = min(row0 + (l & 31), N_NODES - 1);
    int hi = l >> 5;
    f32x16 acc[4];
    #pragma unroll
    for (int ct = 0; ct < 4; ct++)
        #pragma unroll
        for (int r = 0; r < 16; r++) acc[ct][r] = 0.0f;
    const float4* ap = xf + (size_t)crow * 32;
    #pragma unroll
    for (int k0 = 0; k0 < 8; k0++) {
        float4 f0 = ap[(k0 * 2 + hi) * 2];
        float4 f1 = ap[(k0 * 2 + hi) * 2 + 1];
        uint4 au;
        au.x = pk2(f0.x, f0.y); au.y = pk2(f0.z, f0.w);
        au.z = pk2(f1.x, f1.y); au.w = pk2(f1.z, f1.w);
        bf16x8 a = bc8(au);
        #pragma unroll
        for (int ct = 0; ct < 4; ct++) {
            int col = ct * 32 + (l & 31);
            bf16x8 b = bc8(WT[col * 16 + ((k0 * 2 + hi) ^ (col & 15))]);
            acc[ct] = __builtin_amdgcn_mfma_f32_32x32x16_bf16(a, b, acc[ct], 0, 0, 0);
        }
    }
    #pragma unroll
    for (int reg = 0; reg < 16; reg++) {
        int row = row0 + (reg & 3) + 8 * (reg >> 2) + 4 * hi;
        if (row < N_NODES) {
            float d = dinv[row];
            int pw = __builtin_amdgcn_cvt_pk_fp8_f32(acc[0][reg] * d, acc[1][reg] * d, 0, false);
            pw = __builtin_amdgcn_cvt_pk_fp8_f32(acc[2][reg] * d, acc[3][reg] * d, pw, true);
            g1p[(size_t)row * 32 + (l & 31)] = (uint)pw;
        }
    }
}

// g2b = bf16((a1 @ W2) * dinv[row]); a1 phys-layout bf16, w2t phys-permuted
__global__ __launch_bounds__(256) void k_gemm2(const uint4* __restrict__ a1v,
                                               const uint4* __restrict__ w2t,
                                               const float* __restrict__ dinv,
                                               ushort_t* __restrict__ g2b) {
    __shared__ uint4 WT[32 * 16];
    int t = threadIdx.x;
    #pragma unroll
    for (int i = 0; i < 2; i++) {
        int gi = i * 256 + t;
        int c = gi >> 4, g = gi & 15;
        WT[c * 16 + (g ^ (c & 15))] = w2t[gi];
    }
    __syncthreads();
    int w = t >> 6, l = t & 63;
    int row0 = blockIdx.x * 128 + w * 32;
    int crow = min(row0 + (l & 31), N_NODES - 1);
    int hi = l >> 5;
    int col = l & 31;
    f32x16 acc;
    #pragma unroll
    for (int r = 0; r < 16; r++) acc[r] = 0.0f;
    const uint4* ap = a1v + (size_t)crow * 16;
    #pragma unroll
    for (int k0 = 0; k0 < 8; k0++) {
        bf16x8 a = bc8(ap[k0 * 2 + hi]);
        bf16x8 b = bc8(WT[col * 16 + ((k0 * 2 + hi) ^ (col & 15))]);
        acc = __builtin_amdgcn_mfma_f32_32x32x16_bf16(a, b, acc, 0, 0, 0);
    }
    #pragma unroll
    for (int reg = 0; reg < 16; reg++) {
        int row = row0 + (reg & 3) + 8 * (reg >> 2) + 4 * hi;
        if (row < N_NODES) g2b[(size_t)row * 32 + col] = f2bf(acc[reg] * dinv[row]);
    }
}

// ---------------- aggregations ----------------

// a1[v] = bf16(relu(dinv[v]*(g1[v] + sum g1[s]) + b1)), phys col layout.
// 16 lanes per node, uint2 (8 fp8 cols) per lane; unroll ladder 16/4/1.
__global__ __launch_bounds__(256) void k_agg1(const uint2* __restrict__ g1p2,
                                              const float* __restrict__ dinv,
                                              const float* __restrict__ b1,
                                              const int* __restrict__ row_start,
                                              const int* __restrict__ csr_src,
                                              uint4* __restrict__ a1) {
    int v = blockIdx.x * 16 + (threadIdx.x >> 4);
    int L = threadIdx.x & 15;
    float s0, s1, s2, s3, s4, s5, s6, s7;
    {
        uint2 u = g1p2[(size_t)v * 16 + L];
        f32x2 a0 = __builtin_amdgcn_cvt_pk_f32_fp8(u.x, false);
        f32x2 a1f = __builtin_amdgcn_cvt_pk_f32_fp8(u.x, true);
        f32x2 a2 = __builtin_amdgcn_cvt_pk_f32_fp8(u.y, false);
        f32x2 a3 = __builtin_amdgcn_cvt_pk_f32_fp8(u.y, true);
        s0 = a0[0]; s1 = a0[1]; s2 = a1f[0]; s3 = a1f[1];
        s4 = a2[0]; s5 = a2[1]; s6 = a3[0]; s7 = a3[1];
    }
    int jb = row_start[v], je = row_start[v + 1];
    int j = jb;
    for (; j + 16 <= je; j += 16) {
        int idx[16];
        #pragma unroll
        for (int q = 0; q < 16; q++) idx[q] = csr_src[j + q];
        uint2 d[16];
        #pragma unroll
        for (int q = 0; q < 16; q++) d[q] = g1p2[(size_t)idx[q] * 16 + L];
        #pragma unroll
        for (int q = 0; q < 16; q++) {
            f32x2 a0 = __builtin_amdgcn_cvt_pk_f32_fp8(d[q].x, false);
            f32x2 a1f = __builtin_amdgcn_cvt_pk_f32_fp8(d[q].x, true);
            f32x2 a2 = __builtin_amdgcn_cvt_pk_f32_fp8(d[q].y, false);
            f32x2 a3 = __builtin_amdgcn_cvt_pk_f32_fp8(d[q].y, true);
            s0 += a0[0]; s1 += a0[1]; s2 += a1f[0]; s3 += a1f[1];
            s4 += a2[0]; s5 += a2[1]; s6 += a3[0]; s7 += a3[1];
        }
    }
    for (; j + 4 <= je; j += 4) {
        int idx[4];
        #pragma unroll
        for (int q = 0; q < 4; q++) idx[q] = csr_src[j + q];
        uint2 d[4];
        #pragma unroll
        for (int q = 0; q < 4; q++) d[q] = g1p2[(size_t)idx[q] * 16 + L];
        #pragma unroll
        for (int q = 0; q < 4; q++) {
            f32x2 a0 = __builtin_amdgcn_cvt_pk_f32_fp8(d[q].x, false);
            f32x2 a1f = __builtin_amdgcn_cvt_pk_f32_fp8(d[q].x, true);
            f32x2 a2 = __builtin_amdgcn_cvt_pk_f32_fp8(d[q].y, false);
            f32x2 a3 = __builtin_amdgcn_cvt_pk_f32_fp8(d[q].y, true);
            s0 += a0[0]; s1 += a0[1]; s2 += a1f[0]; s3 += a1f[1];
            s4 += a2[0]; s5 += a2[1]; s6 += a3[0]; s7 += a3[1];
        }
    }
    for (; j < je; j++) {
        uint2 u = g1p2[(size_t)csr_src[j] * 16 + L];
        f32x2 a0 = __builtin_amdgcn_cvt_pk_f32_fp8(u.x, false);
        f32x2 a1f = __builtin_amdgcn_cvt_pk_f32_fp8(u.x, true);
        f32x2 a2 = __builtin_amdgcn_cvt_pk_f32_fp8(u.y, false);
        f32x2 a3 = __builtin_amdgcn_cvt_pk_f32_fp8(u.y, true);
        s0 += a0[0]; s1 += a0[1]; s2 += a1f[0]; s3 += a1f[1];
        s4 += a2[0]; s5 += a2[1]; s6 += a3[0]; s7 += a3[1];
    }
    float d = dinv[v];
    // phys p = 8L+q -> logical c = (q&3)*32 + 2L + (q>>2)
    int c0 = 2 * L;
    float o0 = fmaxf(d * s0 + b1[c0], 0.0f);
    float o1 = fmaxf(d * s1 + b1[32 + c0], 0.0f);
    float o2 = fmaxf(d * s2 + b1[64 + c0], 0.0f);
    float o3 = fmaxf(d * s3 + b1[96 + c0], 0.0f);
    float o4 = fmaxf(d * s4 + b1[c0 + 1], 0.0f);
    float o5 = fmaxf(d * s5 + b1[32 + c0 + 1], 0.0f);
    float o6 = fmaxf(d * s6 + b1[64 + c0 + 1], 0.0f);
    float o7 = fmaxf(d * s7 + b1[96 + c0 + 1], 0.0f);
    uint4 ow;
    ow.x = pk2(o0, o1); ow.y = pk2(o2, o3);
    ow.z = pk2(o4, o5); ow.w = pk2(o6, o7);
    a1[(size_t)v * 16 + L] = ow;
}

// out[v] = log_softmax(dinv[v]*(g2[v] + sum g2[s]) + b2); g2 bf16.
// 16 lanes per node, uint (2 bf16 cols) per lane; ladder 16/4/1.
__global__ __launch_bounds__(256) void k_agg2(const uint* __restrict__ g2u,
                                              const float* __restrict__ dinv,
                                              const float* __restrict__ b2,
                                              const int* __restrict__ row_start,
                                              const int* __restrict__ csr_src,
                                              float2* __restrict__ out) {
    int v = blockIdx.x * 16 + (threadIdx.x >> 4);
    int L = threadIdx.x & 15;
    float acc0, acc1;
    {
        uint u = g2u[(size_t)v * 16 + L];
        acc0 = bf2f(u & 0xffffu); acc1 = bf2f(u >> 16);
    }
    int jb = row_start[v], je = row_start[v + 1];
    int j = jb;
    for (; j + 16 <= je; j += 16) {
        int idx[16];
        #pragma unroll
        for (int q = 0; q < 16; q++) idx[q] = csr_src[j + q];
        uint d[16];
        #pragma unroll
        for (int q = 0; q < 16; q++) d[q] = g2u[(size_t)idx[q] * 16 + L];
        #pragma unroll
        for (int q = 0; q < 16; q++) {
            acc0 += bf2f(d[q] & 0xffffu); acc1 += bf2f(d[q] >> 16);
        }
    }
    for (; j + 4 <= je; j += 4) {
        int idx[4];
        #pragma unroll
        for (int q = 0; q < 4; q++) idx[q] = csr_src[j + q];
        uint d[4];
        #pragma unroll
        for (int q = 0; q < 4; q++) d[q] = g2u[(size_t)idx[q] * 16 + L];
        #pragma unroll
        for (int q = 0; q < 4; q++) {
            acc0 += bf2f(d[q] & 0xffffu); acc1 += bf2f(d[q] >> 16);
        }
    }
    for (; j < je; j++) {
        uint u = g2u[(size_t)csr_src[j] * 16 + L];
        acc0 += bf2f(u & 0xffffu); acc1 += bf2f(u >> 16);
    }
    float dv = dinv[v];
    float z0 = dv * acc0 + b2[2 * L];
    float z1 = dv * acc1 + b2[2 * L + 1];
    float m = fmaxf(z0, z1);
    #pragma unroll
    for (int off = 8; off >= 1; off >>= 1) m = fmaxf(m, __shfl_xor(m, off));
    float e = __expf(z0 - m) + __expf(z1 - m);
    #pragma unroll
    for (int off = 8; off >= 1; off >>= 1) e += __shfl_xor(e, off);
    float lg = __logf(e);
    float2 o;
    o.x = (z0 - m) - lg;
    o.y = (z1 - m) - lg;
    out[(size_t)v * 16 + L] = o;
}

// ---------------- launch ----------------

extern "C" void kernel_launch(void* const* d_in, const int* in_sizes, int n_in,
                              void* d_out, int out_size, void* d_ws, size_t ws_size,
                              hipStream_t stream) {
    const float* x  = (const float*)d_in[0];
    const int*   ei = (const int*)d_in[1];
    const float* W1 = (const float*)d_in[2];
    const float* b1 = (const float*)d_in[3];
    const float* W2 = (const float*)d_in[4];
    const float* b2 = (const float*)d_in[5];
    float* out = (float*)d_out;

    char* ws = (char*)d_ws;
    size_t off = 0;
    auto alloc = [&](size_t bytes) {
        void* p = ws + off;
        off = (off + bytes + 255) & ~255ULL;
        return p;
    };
    // zeroed region first (single memset): flag, cnt
    int* flag = (int*)alloc(4);
    int* cnt  = (int*)alloc((size_t)NB * 4);
    size_t zero_bytes = off;
    int*   bbase     = (int*)alloc((size_t)NB * 4);
    int*   row_start = (int*)alloc((size_t)(N_NODES + 1) * 4);
    float* dinv      = (float*)alloc((size_t)N_NODES * 4);
    int*   csr_src   = (int*)alloc((size_t)N_EDGES * 4);
    ushort_t* wt1g   = (ushort_t*)alloc(16384 * 2);
    ushort_t* w2tg   = (ushort_t*)alloc(4096 * 2);
    uint*  g1p       = (uint*)alloc((size_t)N_NODES * 128);      // fp8, reused as g2b (bf16 6.4MB)
    // union region: buf (uint pairs, 12.5MB) -> a1 (bf16 25.6MB); disjoint lifetimes
    size_t ubytes = (size_t)N_NODES * 128 * 2;
    void* uregion = alloc(ubytes);
    uint*  buf = (uint*)uregion;
    uint4* a1  = (uint4*)uregion;
    uint*  g2u = (uint*)g1p;  // g1p dead after k_agg1

    hipMemsetAsync(flag, 0, zero_bytes, stream);

    k_prep<<<80, 256, 0, stream>>>(W1, W2, wt1g, w2tg, ei, flag);
    k_bucket<<<(N_EDGES + CHUNK - 1) / CHUNK, 256, 0, stream>>>(ei, flag, cnt, buf);
    k_bscan<<<1, 256, 0, stream>>>(cnt, bbase, row_start);
    k_build<<<NB, 256, 0, stream>>>(buf, cnt, bbase, row_start, dinv, csr_src);
    k_gemm1<<<(N_NODES + 127) / 128, 256, 0, stream>>>((const float4*)x, (const uint4*)wt1g, dinv, g1p);
    k_agg1<<<N_NODES / 16, 256, 0, stream>>>((const uint2*)g1p, dinv, b1, row_start, csr_src, a1);
    k_gemm2<<<(N_NODES + 127) / 128, 256, 0, stream>>>((const uint4*)a1, (const uint4*)w2tg, dinv, g2u ? (ushort_t*)g2u : nullptr);
    k_agg2<<<N_NODES / 16, 256, 0, stream>>>(g2u, dinv, b2, row_start, csr_src, (float2*)out);
}

// Round 9
// 156.541 us; speedup vs baseline: 3.3871x; 1.0043x over previous
//
#include <hip/hip_runtime.h>
#include <hip/hip_bf16.h>
#include <math.h>

#define N_NODES 100000
#define N_EDGES 1600000
#define NB 196        // buckets of 512 nodes
#define CAP 16000     // per-bucket capacity (mean 8163)
#define CHUNK 4096

typedef unsigned int uint;
typedef unsigned short ushort_t;
typedef float f32x16 __attribute__((ext_vector_type(16)));
typedef float f32x2 __attribute__((ext_vector_type(2)));
typedef __bf16 bf16x8 __attribute__((ext_vector_type(8)));

__device__ __forceinline__ float bf2f(uint h) {
    union { uint u; float f; } x; x.u = h << 16; return x.f;
}
__device__ __forceinline__ unsigned short f2bf(float f) {
    union { float f; uint u; } x; x.f = f;
    uint u = x.u;
    return (unsigned short)((u + 0x7fffu + ((u >> 16) & 1u)) >> 16);  // RNE
}
__device__ __forceinline__ uint pk2(float a, float b) {
    return (uint)f2bf(a) | ((uint)f2bf(b) << 16);
}
__device__ __forceinline__ bf16x8 bc8(uint4 u) { return __builtin_bit_cast(bf16x8, u); }

__device__ __forceinline__ int edge_at(const int* __restrict__ ei, int is32, long long idx) {
    return is32 ? ei[idx] : (int)(((const long long*)ei)[idx]);
}

// ---------------- CSR build via LDS-staged counting sort ----------------
// buf entry: src (17b) | dst_local (9b) << 17

__global__ __launch_bounds__(256) void k_bucket(const int* __restrict__ ei,
                                                const int* __restrict__ flag,
                                                int* __restrict__ cnt,
                                                uint* __restrict__ buf) {
    __shared__ uint stage[CHUNK];
    __shared__ unsigned char bid[CHUNK];
    __shared__ int lcnt[256], ls[256], lbase[256], gbase[256];
    int t = threadIdx.x;
    int is32 = *flag;
    lcnt[t] = 0;
    __syncthreads();
    int base = blockIdx.x * CHUNK;
    int srcv[16], dstv[16], offv[16];
    #pragma unroll
    for (int i = 0; i < 16; i++) {
        int e = base + i * 256 + t;
        if (e < N_EDGES) {
            srcv[i] = edge_at(ei, is32, e);
            dstv[i] = edge_at(ei, is32, (long long)N_EDGES + e);
            offv[i] = atomicAdd(&lcnt[dstv[i] >> 9], 1);
        } else {
            offv[i] = -1;
        }
    }
    __syncthreads();
    int c = lcnt[t];
    ls[t] = c;
    __syncthreads();
    int val = c;
    for (int off = 1; off < 256; off <<= 1) {
        int tmp = (t >= off) ? ls[t - off] : 0;
        __syncthreads();
        val += tmp;
        ls[t] = val;
        __syncthreads();
    }
    lbase[t] = val - c;  // exclusive
    if (c > 0) gbase[t] = atomicAdd(&cnt[t], c); else gbase[t] = 0;
    __syncthreads();
    int total = ls[255];
    #pragma unroll
    for (int i = 0; i < 16; i++) {
        if (offv[i] >= 0) {
            int b = dstv[i] >> 9;
            int p = lbase[b] + offv[i];
            stage[p] = (uint)srcv[i] | ((uint)(dstv[i] & 511) << 17);
            bid[p] = (unsigned char)b;
        }
    }
    __syncthreads();
    for (int idx = t; idx < total; idx += 256) {
        int b = bid[idx];
        int r = gbase[b] + (idx - lbase[b]);
        if (r < CAP) buf[(size_t)b * CAP + r] = stage[idx];
    }
}

// Pass B with inline bucket-prefix scan (bscan folded in).
__global__ __launch_bounds__(256) void k_build(const uint* __restrict__ buf,
                                               const int* __restrict__ cnt,
                                               int* __restrict__ row_start,
                                               float* __restrict__ dinv,
                                               int* __restrict__ csr_src) {
    __shared__ int ldeg[512], lexc[512], lcur[512], s[256];
    int t = threadIdx.x;
    int b = blockIdx.x;
    // prefix scan over cnt[0..NB)
    int cv = (t < NB) ? cnt[t] : 0;
    s[t] = cv;
    __syncthreads();
    int val = cv;
    for (int off = 1; off < 256; off <<= 1) {
        int tmp = (t >= off) ? s[t - off] : 0;
        __syncthreads();
        val += tmp;
        s[t] = val;
        __syncthreads();
    }
    int obase = (b == 0) ? 0 : s[b - 1];
    if (b == 0 && t == 0) row_start[N_NODES] = N_EDGES;
    int n0 = b << 9;
    int nn = min(512, N_NODES - n0);
    int ne = min(cnt[b], CAP);
    const uint* __restrict__ in = buf + (size_t)b * CAP;
    ldeg[t] = 0; ldeg[t + 256] = 0;
    lcur[t] = 0; lcur[t + 256] = 0;
    __syncthreads();
    for (int idx = t; idx < ne; idx += 256) {
        atomicAdd(&ldeg[in[idx] >> 17], 1);
    }
    __syncthreads();
    int v = ldeg[2 * t] + ldeg[2 * t + 1];
    s[t] = v;
    __syncthreads();
    int val2 = v;
    for (int off = 1; off < 256; off <<= 1) {
        int tmp = (t >= off) ? s[t - off] : 0;
        __syncthreads();
        val2 += tmp;
        s[t] = val2;
        __syncthreads();
    }
    int excl = val2 - v;
    lexc[2 * t] = excl;
    lexc[2 * t + 1] = excl + ldeg[2 * t];
    __syncthreads();
    for (int i = t; i < nn; i += 256) {
        row_start[n0 + i] = obase + lexc[i];
        dinv[n0 + i] = rsqrtf((float)(ldeg[i] + 1));  // +1 self loop
    }
    __syncthreads();
    for (int idx = t; idx < ne; idx += 256) {
        uint p = in[idx];
        int dl = p >> 17;
        int pos = obase + lexc[dl] + atomicAdd(&lcur[dl], 1);
        csr_src[pos] = (int)(p & 0x1FFFFu);
    }
}

// ---------------- weight prep (W1^T bf16) + edge dtype detect ----------------
__global__ void k_prep(const float* __restrict__ W1, ushort_t* __restrict__ wt1,
                       const int* __restrict__ ei, int* __restrict__ flag) {
    int t = threadIdx.x;
    if (blockIdx.x == 0) {
        int v = ei[2 * t + 1] | ei[2 * (t + 256) + 1];
        if (v) atomicOr(flag, 1);  // 1 => int32 layout
    }
    int i = blockIdx.x * 256 + t;
    int c = i >> 7, k = i & 127;
    wt1[i] = f2bf(W1[k * 128 + c]);
}

// ---------------- MFMA GEMM 1 ----------------
// mfma_f32_32x32x16_bf16: A row=lane&31,k=(lane>>5)*8+j; B col=lane&31,same k;
// D col=lane&31, row=(reg&3)+8*(reg>>2)+4*(lane>>5)
// g1p = fp8((x @ W1) * dinv[row]), physically col-permuted: phys p=(l&31)*4+ct
__global__ __launch_bounds__(256) void k_gemm1(const float4* __restrict__ xf,
                                               const uint4* __restrict__ wt1,
                                               const float* __restrict__ dinv,
                                               uint* __restrict__ g1p) {
    __shared__ uint4 WT[128 * 16];
    int t = threadIdx.x;
    #pragma unroll
    for (int i = 0; i < 8; i++) {
        int gi = i * 256 + t;
        int c = gi >> 4, g = gi & 15;
        WT[c * 16 + (g ^ (c & 15))] = wt1[gi];   // swizzled store (conflict-free read)
    }
    __syncthreads();
    int w = t >> 6, l = t & 63;
    int row0 = blockIdx.x * 128 + w * 32;
    int crow = min(row0 + (l & 31), N_NODES - 1);
    int hi = l >> 5;
    f32x16 acc[4];
    #pragma unroll
    for (int ct = 0; ct < 4; ct++)
        #pragma unroll
        for (int r = 0; r < 16; r++) acc[ct][r] = 0.0f;
    const float4* ap = xf + (size_t)crow * 32;
    #pragma unroll
    for (int k0 = 0; k0 < 8; k0++) {
        float4 f0 = ap[(k0 * 2 + hi) * 2];
        float4 f1 = ap[(k0 * 2 + hi) * 2 + 1];
        uint4 au;
        au.x = pk2(f0.x, f0.y); au.y = pk2(f0.z, f0.w);
        au.z = pk2(f1.x, f1.y); au.w = pk2(f1.z, f1.w);
        bf16x8 a = bc8(au);
        #pragma unroll
        for (int ct = 0; ct < 4; ct++) {
            int col = ct * 32 + (l & 31);
            bf16x8 b = bc8(WT[col * 16 + ((k0 * 2 + hi) ^ (col & 15))]);
            acc[ct] = __builtin_amdgcn_mfma_f32_32x32x16_bf16(a, b, acc[ct], 0, 0, 0);
        }
    }
    #pragma unroll
    for (int reg = 0; reg < 16; reg++) {
        int row = row0 + (reg & 3) + 8 * (reg >> 2) + 4 * hi;
        if (row < N_NODES) {
            float d = dinv[row];
            int pw = __builtin_amdgcn_cvt_pk_fp8_f32(acc[0][reg] * d, acc[1][reg] * d, 0, false);
            pw = __builtin_amdgcn_cvt_pk_fp8_f32(acc[2][reg] * d, acc[3][reg] * d, pw, true);
            g1p[(size_t)row * 32 + (l & 31)] = (uint)pw;
        }
    }
}

// ---------------- fused agg1 + layer-2 matvec ----------------
// Per node v (16 lanes): gather-sum fp8 g1 rows -> a1 row (relu, f32) -> LDS ->
// matvec vs LDS W2 (f32) -> g2 row (fp8, 32B).
// phys p = 8L+q -> logical c: q=0..3 -> q*32+2L ; q=4..7 -> (q-4)*32+2L+1
__global__ __launch_bounds__(256) void k_agg1(const uint2* __restrict__ g1p2,
                                              const float* __restrict__ dinv,
                                              const float* __restrict__ b1,
                                              const float* __restrict__ W2,
                                              const int* __restrict__ row_start,
                                              const int* __restrict__ csr_src,
                                              ushort_t* __restrict__ g2p) {
    __shared__ float Ws2[128 * 32];   // 16KB, plain [k][c]
    __shared__ float As[16][132];     // 8.25KB, padded (+4) to dodge group-bank aliasing
    int t = threadIdx.x;
    #pragma unroll
    for (int i = 0; i < 16; i++) Ws2[i * 256 + t] = W2[i * 256 + t];
    int g = t >> 4;
    int L = t & 15;
    int v = blockIdx.x * 16 + g;
    float s0, s1, s2, s3, s4, s5, s6, s7;
    {
        uint2 u = g1p2[(size_t)v * 16 + L];
        f32x2 a0 = __builtin_amdgcn_cvt_pk_f32_fp8(u.x, false);
        f32x2 a1f = __builtin_amdgcn_cvt_pk_f32_fp8(u.x, true);
        f32x2 a2 = __builtin_amdgcn_cvt_pk_f32_fp8(u.y, false);
        f32x2 a3 = __builtin_amdgcn_cvt_pk_f32_fp8(u.y, true);
        s0 = a0[0]; s1 = a0[1]; s2 = a1f[0]; s3 = a1f[1];
        s4 = a2[0]; s5 = a2[1]; s6 = a3[0]; s7 = a3[1];
    }
    int jb = row_start[v], je = row_start[v + 1];
    int j = jb;
    for (; j + 8 <= je; j += 8) {
        int i0 = csr_src[j + 0], i1 = csr_src[j + 1];
        int i2 = csr_src[j + 2], i3 = csr_src[j + 3];
        int i4 = csr_src[j + 4], i5 = csr_src[j + 5];
        int i6 = csr_src[j + 6], i7 = csr_src[j + 7];
        uint2 d0 = g1p2[(size_t)i0 * 16 + L];
        uint2 d1 = g1p2[(size_t)i1 * 16 + L];
        uint2 d2 = g1p2[(size_t)i2 * 16 + L];
        uint2 d3 = g1p2[(size_t)i3 * 16 + L];
        uint2 d4 = g1p2[(size_t)i4 * 16 + L];
        uint2 d5 = g1p2[(size_t)i5 * 16 + L];
        uint2 d6 = g1p2[(size_t)i6 * 16 + L];
        uint2 d7 = g1p2[(size_t)i7 * 16 + L];
        #pragma unroll
        for (int q = 0; q < 8; q++) {
            uint2 uu = q == 0 ? d0 : q == 1 ? d1 : q == 2 ? d2 : q == 3 ? d3
                     : q == 4 ? d4 : q == 5 ? d5 : q == 6 ? d6 : d7;
            f32x2 a0 = __builtin_amdgcn_cvt_pk_f32_fp8(uu.x, false);
            f32x2 a1f = __builtin_amdgcn_cvt_pk_f32_fp8(uu.x, true);
            f32x2 a2 = __builtin_amdgcn_cvt_pk_f32_fp8(uu.y, false);
            f32x2 a3 = __builtin_amdgcn_cvt_pk_f32_fp8(uu.y, true);
            s0 += a0[0]; s1 += a0[1]; s2 += a1f[0]; s3 += a1f[1];
            s4 += a2[0]; s5 += a2[1]; s6 += a3[0]; s7 += a3[1];
        }
    }
    for (; j < je; j++) {
        uint2 u = g1p2[(size_t)csr_src[j] * 16 + L];
        f32x2 a0 = __builtin_amdgcn_cvt_pk_f32_fp8(u.x, false);
        f32x2 a1f = __builtin_amdgcn_cvt_pk_f32_fp8(u.x, true);
        f32x2 a2 = __builtin_amdgcn_cvt_pk_f32_fp8(u.y, false);
        f32x2 a3 = __builtin_amdgcn_cvt_pk_f32_fp8(u.y, true);
        s0 += a0[0]; s1 += a0[1]; s2 += a1f[0]; s3 += a1f[1];
        s4 += a2[0]; s5 += a2[1]; s6 += a3[0]; s7 += a3[1];
    }
    float d = dinv[v];
    int c0 = 2 * L;
    float o0 = fmaxf(d * s0 + b1[c0], 0.0f);
    float o1 = fmaxf(d * s1 + b1[32 + c0], 0.0f);
    float o2 = fmaxf(d * s2 + b1[64 + c0], 0.0f);
    float o3 = fmaxf(d * s3 + b1[96 + c0], 0.0f);
    float o4 = fmaxf(d * s4 + b1[c0 + 1], 0.0f);
    float o5 = fmaxf(d * s5 + b1[32 + c0 + 1], 0.0f);
    float o6 = fmaxf(d * s6 + b1[64 + c0 + 1], 0.0f);
    float o7 = fmaxf(d * s7 + b1[96 + c0 + 1], 0.0f);
    As[g][c0]          = o0;
    As[g][32 + c0]     = o1;
    As[g][64 + c0]     = o2;
    As[g][96 + c0]     = o3;
    As[g][c0 + 1]      = o4;
    As[g][32 + c0 + 1] = o5;
    As[g][64 + c0 + 1] = o6;
    As[g][96 + c0 + 1] = o7;
    __syncthreads();
    float acc0 = 0.0f, acc1 = 0.0f;
    #pragma unroll 8
    for (int k = 0; k < 128; k++) {
        float a = As[g][k];
        acc0 += a * Ws2[k * 32 + c0];
        acc1 += a * Ws2[k * 32 + c0 + 1];
    }
    // g2[v][2L], g2[v][2L+1] as fp8 -> bytes 2L,2L+1 of the 32B row
    int pw = __builtin_amdgcn_cvt_pk_fp8_f32(acc0 * d, acc1 * d, 0, false);
    g2p[(size_t)v * 16 + L] = (ushort_t)(pw & 0xffff);
}

// ---------------- agg2 + log_softmax (fp8 g2, 32B rows) ----------------
// 8 lanes/node, lane L holds cols 4L..4L+3 (one uint of fp8).
__global__ __launch_bounds__(256) void k_agg2(const uint* __restrict__ g2p4,
                                              const float* __restrict__ dinv,
                                              const float* __restrict__ b2,
                                              const int* __restrict__ row_start,
                                              const int* __restrict__ csr_src,
                                              float4* __restrict__ out) {
    int v = blockIdx.x * 32 + (threadIdx.x >> 3);
    int L = threadIdx.x & 7;
    float s0, s1, s2, s3;
    {
        uint u = g2p4[(size_t)v * 8 + L];
        f32x2 a0 = __builtin_amdgcn_cvt_pk_f32_fp8(u, false);
        f32x2 a1f = __builtin_amdgcn_cvt_pk_f32_fp8(u, true);
        s0 = a0[0]; s1 = a0[1]; s2 = a1f[0]; s3 = a1f[1];
    }
    int jb = row_start[v], je = row_start[v + 1];
    int j = jb;
    for (; j + 8 <= je; j += 8) {
        int i0 = csr_src[j + 0], i1 = csr_src[j + 1];
        int i2 = csr_src[j + 2], i3 = csr_src[j + 3];
        int i4 = csr_src[j + 4], i5 = csr_src[j + 5];
        int i6 = csr_src[j + 6], i7 = csr_src[j + 7];
        uint d0 = g2p4[(size_t)i0 * 8 + L];
        uint d1 = g2p4[(size_t)i1 * 8 + L];
        uint d2 = g2p4[(size_t)i2 * 8 + L];
        uint d3 = g2p4[(size_t)i3 * 8 + L];
        uint d4 = g2p4[(size_t)i4 * 8 + L];
        uint d5 = g2p4[(size_t)i5 * 8 + L];
        uint d6 = g2p4[(size_t)i6 * 8 + L];
        uint d7 = g2p4[(size_t)i7 * 8 + L];
        #pragma unroll
        for (int q = 0; q < 8; q++) {
            uint uu = q == 0 ? d0 : q == 1 ? d1 : q == 2 ? d2 : q == 3 ? d3
                    : q == 4 ? d4 : q == 5 ? d5 : q == 6 ? d6 : d7;
            f32x2 a0 = __builtin_amdgcn_cvt_pk_f32_fp8(uu, false);
            f32x2 a1f = __builtin_amdgcn_cvt_pk_f32_fp8(uu, true);
            s0 += a0[0]; s1 += a0[1]; s2 += a1f[0]; s3 += a1f[1];
        }
    }
    for (; j < je; j++) {
        uint u = g2p4[(size_t)csr_src[j] * 8 + L];
        f32x2 a0 = __builtin_amdgcn_cvt_pk_f32_fp8(u, false);
        f32x2 a1f = __builtin_amdgcn_cvt_pk_f32_fp8(u, true);
        s0 += a0[0]; s1 += a0[1]; s2 += a1f[0]; s3 += a1f[1];
    }
    float dv = dinv[v];
    int c0 = 4 * L;
    float z0 = dv * s0 + b2[c0];
    float z1 = dv * s1 + b2[c0 + 1];
    float z2 = dv * s2 + b2[c0 + 2];
    float z3 = dv * s3 + b2[c0 + 3];
    float m = fmaxf(fmaxf(z0, z1), fmaxf(z2, z3));
    #pragma unroll
    for (int off = 4; off >= 1; off >>= 1) m = fmaxf(m, __shfl_xor(m, off));
    float e = __expf(z0 - m) + __expf(z1 - m) + __expf(z2 - m) + __expf(z3 - m);
    #pragma unroll
    for (int off = 4; off >= 1; off >>= 1) e += __shfl_xor(e, off);
    float lg = __logf(e);
    float4 o;
    o.x = (z0 - m) - lg;
    o.y = (z1 - m) - lg;
    o.z = (z2 - m) - lg;
    o.w = (z3 - m) - lg;
    out[(size_t)v * 8 + L] = o;
}

// ---------------- launch ----------------

extern "C" void kernel_launch(void* const* d_in, const int* in_sizes, int n_in,
                              void* d_out, int out_size, void* d_ws, size_t ws_size,
                              hipStream_t stream) {
    const float* x  = (const float*)d_in[0];
    const int*   ei = (const int*)d_in[1];
    const float* W1 = (const float*)d_in[2];
    const float* b1 = (const float*)d_in[3];
    const float* W2 = (const float*)d_in[4];
    const float* b2 = (const float*)d_in[5];
    float* out = (float*)d_out;

    char* ws = (char*)d_ws;
    size_t off = 0;
    auto alloc = [&](size_t bytes) {
        void* p = ws + off;
        off = (off + bytes + 255) & ~255ULL;
        return p;
    };
    // zeroed region first (single memset): flag, cnt
    int* flag = (int*)alloc(4);
    int* cnt  = (int*)alloc((size_t)NB * 4);
    size_t zero_bytes = off;
    int*   row_start = (int*)alloc((size_t)(N_NODES + 1) * 4);
    float* dinv      = (float*)alloc((size_t)N_NODES * 4);
    int*   csr_src   = (int*)alloc((size_t)N_EDGES * 4);
    ushort_t* wt1g   = (ushort_t*)alloc(16384 * 2);
    uint*  g1p       = (uint*)alloc((size_t)N_NODES * 128);   // fp8 L1 acts, 12.8MB
    ushort_t* g2p    = (ushort_t*)alloc((size_t)N_NODES * 32); // fp8 L2 pre-acts, 3.2MB
    uint*  buf       = (uint*)alloc((size_t)NB * CAP * 4);     // 12.5MB sort staging

    hipMemsetAsync(flag, 0, zero_bytes, stream);

    k_prep<<<64, 256, 0, stream>>>(W1, wt1g, ei, flag);
    k_bucket<<<(N_EDGES + CHUNK - 1) / CHUNK, 256, 0, stream>>>(ei, flag, cnt, buf);
    k_build<<<NB, 256, 0, stream>>>(buf, cnt, row_start, dinv, csr_src);
    k_gemm1<<<(N_NODES + 127) / 128, 256, 0, stream>>>((const float4*)x, (const uint4*)wt1g, dinv, g1p);
    k_agg1<<<N_NODES / 16, 256, 0, stream>>>((const uint2*)g1p, dinv, b1, W2, row_start, csr_src, g2p);
    k_agg2<<<N_NODES / 32, 256, 0, stream>>>((const uint*)g2p, dinv, b2, row_start, csr_src, (float4*)out);
}

// Round 10
// 147.082 us; speedup vs baseline: 3.6049x; 1.0643x over previous
//
#include <hip/hip_runtime.h>
#include <hip/hip_bf16.h>
#include <math.h>

#define N_NODES 100000
#define N_EDGES 1600000
#define NB 196        // buckets of 512 nodes
#define CAP 16000     // per-bucket capacity (mean 8163)
#define CHUNK 4096

typedef unsigned int uint;
typedef unsigned short ushort_t;
typedef unsigned char uchar_t;
typedef float f32x16 __attribute__((ext_vector_type(16)));
typedef float f32x2 __attribute__((ext_vector_type(2)));
typedef __bf16 bf16x8 __attribute__((ext_vector_type(8)));

__device__ __forceinline__ float bf2f(uint h) {
    union { uint u; float f; } x; x.u = h << 16; return x.f;
}
__device__ __forceinline__ unsigned short f2bf(float f) {
    union { float f; uint u; } x; x.f = f;
    uint u = x.u;
    return (unsigned short)((u + 0x7fffu + ((u >> 16) & 1u)) >> 16);  // RNE
}
__device__ __forceinline__ uint pk2(float a, float b) {
    return (uint)f2bf(a) | ((uint)f2bf(b) << 16);
}
__device__ __forceinline__ bf16x8 bc8(uint4 u) { return __builtin_bit_cast(bf16x8, u); }

__device__ __forceinline__ int edge_at(const int* __restrict__ ei, int is32, long long idx) {
    return is32 ? ei[idx] : (int)(((const long long*)ei)[idx]);
}

// ---------------- CSR build via LDS-staged counting sort ----------------
// buf entry: src (17b) | dst_local (9b) << 17

__global__ __launch_bounds__(256) void k_bucket(const int* __restrict__ ei,
                                                const int* __restrict__ flag,
                                                int* __restrict__ cnt,
                                                uint* __restrict__ buf) {
    __shared__ uint stage[CHUNK];
    __shared__ unsigned char bid[CHUNK];
    __shared__ int lcnt[256], ls[256], lbase[256], gbase[256];
    int t = threadIdx.x;
    int is32 = *flag;
    lcnt[t] = 0;
    __syncthreads();
    int base = blockIdx.x * CHUNK;
    int srcv[16], dstv[16], offv[16];
    #pragma unroll
    for (int i = 0; i < 16; i++) {
        int e = base + i * 256 + t;
        if (e < N_EDGES) {
            srcv[i] = edge_at(ei, is32, e);
            dstv[i] = edge_at(ei, is32, (long long)N_EDGES + e);
            offv[i] = atomicAdd(&lcnt[dstv[i] >> 9], 1);
        } else {
            offv[i] = -1;
        }
    }
    __syncthreads();
    int c = lcnt[t];
    ls[t] = c;
    __syncthreads();
    int val = c;
    for (int off = 1; off < 256; off <<= 1) {
        int tmp = (t >= off) ? ls[t - off] : 0;
        __syncthreads();
        val += tmp;
        ls[t] = val;
        __syncthreads();
    }
    lbase[t] = val - c;  // exclusive
    if (c > 0) gbase[t] = atomicAdd(&cnt[t], c); else gbase[t] = 0;
    __syncthreads();
    int total = ls[255];
    #pragma unroll
    for (int i = 0; i < 16; i++) {
        if (offv[i] >= 0) {
            int b = dstv[i] >> 9;
            int p = lbase[b] + offv[i];
            stage[p] = (uint)srcv[i] | ((uint)(dstv[i] & 511) << 17);
            bid[p] = (unsigned char)b;
        }
    }
    __syncthreads();
    for (int idx = t; idx < total; idx += 256) {
        int b = bid[idx];
        int r = gbase[b] + (idx - lbase[b]);
        if (r < CAP) buf[(size_t)b * CAP + r] = stage[idx];
    }
}

// Pass B with inline bucket-prefix scan.
__global__ __launch_bounds__(256) void k_build(const uint* __restrict__ buf,
                                               const int* __restrict__ cnt,
                                               int* __restrict__ row_start,
                                               float* __restrict__ dinv,
                                               int* __restrict__ csr_src) {
    __shared__ int ldeg[512], lexc[512], lcur[512], s[256];
    int t = threadIdx.x;
    int b = blockIdx.x;
    int cv = (t < NB) ? cnt[t] : 0;
    s[t] = cv;
    __syncthreads();
    int val = cv;
    for (int off = 1; off < 256; off <<= 1) {
        int tmp = (t >= off) ? s[t - off] : 0;
        __syncthreads();
        val += tmp;
        s[t] = val;
        __syncthreads();
    }
    int obase = (b == 0) ? 0 : s[b - 1];
    if (b == 0 && t == 0) row_start[N_NODES] = N_EDGES;
    int n0 = b << 9;
    int nn = min(512, N_NODES - n0);
    int ne = min(cnt[b], CAP);
    const uint* __restrict__ in = buf + (size_t)b * CAP;
    ldeg[t] = 0; ldeg[t + 256] = 0;
    lcur[t] = 0; lcur[t + 256] = 0;
    __syncthreads();
    for (int idx = t; idx < ne; idx += 256) {
        atomicAdd(&ldeg[in[idx] >> 17], 1);
    }
    __syncthreads();
    int v = ldeg[2 * t] + ldeg[2 * t + 1];
    s[t] = v;
    __syncthreads();
    int val2 = v;
    for (int off = 1; off < 256; off <<= 1) {
        int tmp = (t >= off) ? s[t - off] : 0;
        __syncthreads();
        val2 += tmp;
        s[t] = val2;
        __syncthreads();
    }
    int excl = val2 - v;
    lexc[2 * t] = excl;
    lexc[2 * t + 1] = excl + ldeg[2 * t];
    __syncthreads();
    for (int i = t; i < nn; i += 256) {
        row_start[n0 + i] = obase + lexc[i];
        dinv[n0 + i] = rsqrtf((float)(ldeg[i] + 1));  // +1 self loop
    }
    __syncthreads();
    for (int idx = t; idx < ne; idx += 256) {
        uint p = in[idx];
        int dl = p >> 17;
        int pos = obase + lexc[dl] + atomicAdd(&lcur[dl], 1);
        csr_src[pos] = (int)(p & 0x1FFFFu);
    }
}

// ---------------- weight prep (+ edge dtype detect in block 0) ----------------
// wt1[c][k] = bf16(W1[k][c]); w2t[c][p] = bf16(W2[cl(p)][c]), cl(p)=(p&3)*32+(p>>2)
__global__ void k_prep(const float* __restrict__ W1, const float* __restrict__ W2,
                       ushort_t* __restrict__ wt1, ushort_t* __restrict__ w2t,
                       const int* __restrict__ ei, int* __restrict__ flag) {
    int t = threadIdx.x;
    if (blockIdx.x == 0) {
        int v = ei[2 * t + 1] | ei[2 * (t + 256) + 1];
        if (v) atomicOr(flag, 1);  // 1 => int32 layout
    }
    int i = blockIdx.x * 256 + t;
    if (i < 16384) {
        int c = i >> 7, k = i & 127;
        wt1[i] = f2bf(W1[k * 128 + c]);
    } else if (i < 20480) {
        int j = i - 16384;
        int c = j >> 7, p = j & 127;
        int cl = (p & 3) * 32 + (p >> 2);
        w2t[j] = f2bf(W2[cl * 32 + c]);
    }
}

// ---------------- MFMA GEMM 1 ----------------
// mfma_f32_32x32x16_bf16: A row=lane&31,k=(lane>>5)*8+j; B col=lane&31,same k;
// D col=lane&31, row=(reg&3)+8*(reg>>2)+4*(lane>>5)
// g1p = fp8((x @ W1) * dinv[row]), physically col-permuted: phys p=(l&31)*4+ct
__global__ __launch_bounds__(256) void k_gemm1(const float4* __restrict__ xf,
                                               const uint4* __restrict__ wt1,
                                               const float* __restrict__ dinv,
                                               uint* __restrict__ g1p) {
    __shared__ uint4 WT[128 * 16];
    int t = threadIdx.x;
    #pragma unroll
    for (int i = 0; i < 8; i++) {
        int gi = i * 256 + t;
        int c = gi >> 4, g = gi & 15;
        WT[c * 16 + (g ^ (c & 15))] = wt1[gi];   // swizzled store (conflict-free read)
    }
    __syncthreads();
    int w = t >> 6, l = t & 63;
    int row0 = blockIdx.x * 128 + w * 32;
    int crow = min(row0 + (l & 31), N_NODES - 1);
    int hi = l >> 5;
    f32x16 acc[4];
    #pragma unroll
    for (int ct = 0; ct < 4; ct++)
        #pragma unroll
        for (int r = 0; r < 16; r++) acc[ct][r] = 0.0f;
    const float4* ap = xf + (size_t)crow * 32;
    #pragma unroll
    for (int k0 = 0; k0 < 8; k0++) {
        float4 f0 = ap[(k0 * 2 + hi) * 2];
        float4 f1 = ap[(k0 * 2 + hi) * 2 + 1];
        uint4 au;
        au.x = pk2(f0.x, f0.y); au.y = pk2(f0.z, f0.w);
        au.z = pk2(f1.x, f1.y); au.w = pk2(f1.z, f1.w);
        bf16x8 a = bc8(au);
        #pragma unroll
        for (int ct = 0; ct < 4; ct++) {
            int col = ct * 32 + (l & 31);
            bf16x8 b = bc8(WT[col * 16 + ((k0 * 2 + hi) ^ (col & 15))]);
            acc[ct] = __builtin_amdgcn_mfma_f32_32x32x16_bf16(a, b, acc[ct], 0, 0, 0);
        }
    }
    #pragma unroll
    for (int reg = 0; reg < 16; reg++) {
        int row = row0 + (reg & 3) + 8 * (reg >> 2) + 4 * hi;
        if (row < N_NODES) {
            float d = dinv[row];
            int pw = __builtin_amdgcn_cvt_pk_fp8_f32(acc[0][reg] * d, acc[1][reg] * d, 0, false);
            pw = __builtin_amdgcn_cvt_pk_fp8_f32(acc[2][reg] * d, acc[3][reg] * d, pw, true);
            g1p[(size_t)row * 32 + (l & 31)] = (uint)pw;
        }
    }
}

// ---------------- agg1: gather fp8 g1 -> a1 bf16 (phys layout) ----------------
// 16 lanes per node, uint2 (8 fp8 cols) per lane; unroll ladder 16/4/1.
// phys p = 8L+q -> logical c: q<4 -> q*32+2L ; q>=4 -> (q-4)*32+2L+1
__global__ __launch_bounds__(256) void k_agg1(const uint2* __restrict__ g1p2,
                                              const float* __restrict__ dinv,
                                              const float* __restrict__ b1,
                                              const int* __restrict__ row_start,
                                              const int* __restrict__ csr_src,
                                              uint4* __restrict__ a1) {
    int v = blockIdx.x * 16 + (threadIdx.x >> 4);
    int L = threadIdx.x & 15;
    float s0, s1, s2, s3, s4, s5, s6, s7;
    {
        uint2 u = g1p2[(size_t)v * 16 + L];
        f32x2 a0 = __builtin_amdgcn_cvt_pk_f32_fp8(u.x, false);
        f32x2 a1f = __builtin_amdgcn_cvt_pk_f32_fp8(u.x, true);
        f32x2 a2 = __builtin_amdgcn_cvt_pk_f32_fp8(u.y, false);
        f32x2 a3 = __builtin_amdgcn_cvt_pk_f32_fp8(u.y, true);
        s0 = a0[0]; s1 = a0[1]; s2 = a1f[0]; s3 = a1f[1];
        s4 = a2[0]; s5 = a2[1]; s6 = a3[0]; s7 = a3[1];
    }
    int jb = row_start[v], je = row_start[v + 1];
    int j = jb;
    for (; j + 16 <= je; j += 16) {
        int idx[16];
        #pragma unroll
        for (int q = 0; q < 16; q++) idx[q] = csr_src[j + q];
        uint2 d[16];
        #pragma unroll
        for (int q = 0; q < 16; q++) d[q] = g1p2[(size_t)idx[q] * 16 + L];
        #pragma unroll
        for (int q = 0; q < 16; q++) {
            f32x2 a0 = __builtin_amdgcn_cvt_pk_f32_fp8(d[q].x, false);
            f32x2 a1f = __builtin_amdgcn_cvt_pk_f32_fp8(d[q].x, true);
            f32x2 a2 = __builtin_amdgcn_cvt_pk_f32_fp8(d[q].y, false);
            f32x2 a3 = __builtin_amdgcn_cvt_pk_f32_fp8(d[q].y, true);
            s0 += a0[0]; s1 += a0[1]; s2 += a1f[0]; s3 += a1f[1];
            s4 += a2[0]; s5 += a2[1]; s6 += a3[0]; s7 += a3[1];
        }
    }
    for (; j + 4 <= je; j += 4) {
        int idx[4];
        #pragma unroll
        for (int q = 0; q < 4; q++) idx[q] = csr_src[j + q];
        uint2 d[4];
        #pragma unroll
        for (int q = 0; q < 4; q++) d[q] = g1p2[(size_t)idx[q] * 16 + L];
        #pragma unroll
        for (int q = 0; q < 4; q++) {
            f32x2 a0 = __builtin_amdgcn_cvt_pk_f32_fp8(d[q].x, false);
            f32x2 a1f = __builtin_amdgcn_cvt_pk_f32_fp8(d[q].x, true);
            f32x2 a2 = __builtin_amdgcn_cvt_pk_f32_fp8(d[q].y, false);
            f32x2 a3 = __builtin_amdgcn_cvt_pk_f32_fp8(d[q].y, true);
            s0 += a0[0]; s1 += a0[1]; s2 += a1f[0]; s3 += a1f[1];
            s4 += a2[0]; s5 += a2[1]; s6 += a3[0]; s7 += a3[1];
        }
    }
    for (; j < je; j++) {
        uint2 u = g1p2[(size_t)csr_src[j] * 16 + L];
        f32x2 a0 = __builtin_amdgcn_cvt_pk_f32_fp8(u.x, false);
        f32x2 a1f = __builtin_amdgcn_cvt_pk_f32_fp8(u.x, true);
        f32x2 a2 = __builtin_amdgcn_cvt_pk_f32_fp8(u.y, false);
        f32x2 a3 = __builtin_amdgcn_cvt_pk_f32_fp8(u.y, true);
        s0 += a0[0]; s1 += a0[1]; s2 += a1f[0]; s3 += a1f[1];
        s4 += a2[0]; s5 += a2[1]; s6 += a3[0]; s7 += a3[1];
    }
    float d = dinv[v];
    int c0 = 2 * L;
    float o0 = fmaxf(d * s0 + b1[c0], 0.0f);
    float o1 = fmaxf(d * s1 + b1[32 + c0], 0.0f);
    float o2 = fmaxf(d * s2 + b1[64 + c0], 0.0f);
    float o3 = fmaxf(d * s3 + b1[96 + c0], 0.0f);
    float o4 = fmaxf(d * s4 + b1[c0 + 1], 0.0f);
    float o5 = fmaxf(d * s5 + b1[32 + c0 + 1], 0.0f);
    float o6 = fmaxf(d * s6 + b1[64 + c0 + 1], 0.0f);
    float o7 = fmaxf(d * s7 + b1[96 + c0 + 1], 0.0f);
    uint4 ow;
    ow.x = pk2(o0, o1); ow.y = pk2(o2, o3);
    ow.z = pk2(o4, o5); ow.w = pk2(o6, o7);
    a1[(size_t)v * 16 + L] = ow;
}

// ---------------- MFMA GEMM 2: g2p = fp8((a1 @ W2) * dinv) ----------------
// a1 phys-layout bf16, w2t phys-permuted; epilogue byte-stores (byte index = col).
__global__ __launch_bounds__(256) void k_gemm2(const uint4* __restrict__ a1v,
                                               const uint4* __restrict__ w2t,
                                               const float* __restrict__ dinv,
                                               uchar_t* __restrict__ g2p) {
    __shared__ uint4 WT[32 * 16];
    int t = threadIdx.x;
    #pragma unroll
    for (int i = 0; i < 2; i++) {
        int gi = i * 256 + t;
        int c = gi >> 4, g = gi & 15;
        WT[c * 16 + (g ^ (c & 15))] = w2t[gi];
    }
    __syncthreads();
    int w = t >> 6, l = t & 63;
    int row0 = blockIdx.x * 128 + w * 32;
    int crow = min(row0 + (l & 31), N_NODES - 1);
    int hi = l >> 5;
    int col = l & 31;
    f32x16 acc;
    #pragma unroll
    for (int r = 0; r < 16; r++) acc[r] = 0.0f;
    const uint4* ap = a1v + (size_t)crow * 16;
    #pragma unroll
    for (int k0 = 0; k0 < 8; k0++) {
        bf16x8 a = bc8(ap[k0 * 2 + hi]);
        bf16x8 b = bc8(WT[col * 16 + ((k0 * 2 + hi) ^ (col & 15))]);
        acc = __builtin_amdgcn_mfma_f32_32x32x16_bf16(a, b, acc, 0, 0, 0);
    }
    #pragma unroll
    for (int reg = 0; reg < 16; reg++) {
        int row = row0 + (reg & 3) + 8 * (reg >> 2) + 4 * hi;
        if (row < N_NODES) {
            float z = acc[reg] * dinv[row];
            int pw = __builtin_amdgcn_cvt_pk_fp8_f32(z, z, 0, false);
            g2p[(size_t)row * 32 + col] = (uchar_t)(pw & 0xff);
        }
    }
}

// ---------------- agg2 + log_softmax (fp8 g2, 32B rows) ----------------
// 8 lanes/node, lane L holds cols 4L..4L+3 (one uint of fp8).
__global__ __launch_bounds__(256) void k_agg2(const uint* __restrict__ g2p4,
                                              const float* __restrict__ dinv,
                                              const float* __restrict__ b2,
                                              const int* __restrict__ row_start,
                                              const int* __restrict__ csr_src,
                                              float4* __restrict__ out) {
    int v = blockIdx.x * 32 + (threadIdx.x >> 3);
    int L = threadIdx.x & 7;
    float s0, s1, s2, s3;
    {
        uint u = g2p4[(size_t)v * 8 + L];
        f32x2 a0 = __builtin_amdgcn_cvt_pk_f32_fp8(u, false);
        f32x2 a1f = __builtin_amdgcn_cvt_pk_f32_fp8(u, true);
        s0 = a0[0]; s1 = a0[1]; s2 = a1f[0]; s3 = a1f[1];
    }
    int jb = row_start[v], je = row_start[v + 1];
    int j = jb;
    for (; j + 8 <= je; j += 8) {
        int i0 = csr_src[j + 0], i1 = csr_src[j + 1];
        int i2 = csr_src[j + 2], i3 = csr_src[j + 3];
        int i4 = csr_src[j + 4], i5 = csr_src[j + 5];
        int i6 = csr_src[j + 6], i7 = csr_src[j + 7];
        uint d0 = g2p4[(size_t)i0 * 8 + L];
        uint d1 = g2p4[(size_t)i1 * 8 + L];
        uint d2 = g2p4[(size_t)i2 * 8 + L];
        uint d3 = g2p4[(size_t)i3 * 8 + L];
        uint d4 = g2p4[(size_t)i4 * 8 + L];
        uint d5 = g2p4[(size_t)i5 * 8 + L];
        uint d6 = g2p4[(size_t)i6 * 8 + L];
        uint d7 = g2p4[(size_t)i7 * 8 + L];
        #pragma unroll
        for (int q = 0; q < 8; q++) {
            uint uu = q == 0 ? d0 : q == 1 ? d1 : q == 2 ? d2 : q == 3 ? d3
                    : q == 4 ? d4 : q == 5 ? d5 : q == 6 ? d6 : d7;
            f32x2 a0 = __builtin_amdgcn_cvt_pk_f32_fp8(uu, false);
            f32x2 a1f = __builtin_amdgcn_cvt_pk_f32_fp8(uu, true);
            s0 += a0[0]; s1 += a0[1]; s2 += a1f[0]; s3 += a1f[1];
        }
    }
    for (; j < je; j++) {
        uint u = g2p4[(size_t)csr_src[j] * 8 + L];
        f32x2 a0 = __builtin_amdgcn_cvt_pk_f32_fp8(u, false);
        f32x2 a1f = __builtin_amdgcn_cvt_pk_f32_fp8(u, true);
        s0 += a0[0]; s1 += a0[1]; s2 += a1f[0]; s3 += a1f[1];
    }
    float dv = dinv[v];
    int c0 = 4 * L;
    float z0 = dv * s0 + b2[c0];
    float z1 = dv * s1 + b2[c0 + 1];
    float z2 = dv * s2 + b2[c0 + 2];
    float z3 = dv * s3 + b2[c0 + 3];
    float m = fmaxf(fmaxf(z0, z1), fmaxf(z2, z3));
    #pragma unroll
    for (int off = 4; off >= 1; off >>= 1) m = fmaxf(m, __shfl_xor(m, off));
    float e = __expf(z0 - m) + __expf(z1 - m) + __expf(z2 - m) + __expf(z3 - m);
    #pragma unroll
    for (int off = 4; off >= 1; off >>= 1) e += __shfl_xor(e, off);
    float lg = __logf(e);
    float4 o;
    o.x = (z0 - m) - lg;
    o.y = (z1 - m) - lg;
    o.z = (z2 - m) - lg;
    o.w = (z3 - m) - lg;
    out[(size_t)v * 8 + L] = o;
}

// ---------------- launch ----------------

extern "C" void kernel_launch(void* const* d_in, const int* in_sizes, int n_in,
                              void* d_out, int out_size, void* d_ws, size_t ws_size,
                              hipStream_t stream) {
    const float* x  = (const float*)d_in[0];
    const int*   ei = (const int*)d_in[1];
    const float* W1 = (const float*)d_in[2];
    const float* b1 = (const float*)d_in[3];
    const float* W2 = (const float*)d_in[4];
    const float* b2 = (const float*)d_in[5];
    float* out = (float*)d_out;

    char* ws = (char*)d_ws;
    size_t off = 0;
    auto alloc = [&](size_t bytes) {
        void* p = ws + off;
        off = (off + bytes + 255) & ~255ULL;
        return p;
    };
    // zeroed region first (single memset): flag, cnt
    int* flag = (int*)alloc(4);
    int* cnt  = (int*)alloc((size_t)NB * 4);
    size_t zero_bytes = off;
    int*   row_start = (int*)alloc((size_t)(N_NODES + 1) * 4);
    float* dinv      = (float*)alloc((size_t)N_NODES * 4);
    int*   csr_src   = (int*)alloc((size_t)N_EDGES * 4);
    ushort_t* wt1g   = (ushort_t*)alloc(16384 * 2);
    ushort_t* w2tg   = (ushort_t*)alloc(4096 * 2);
    uint*  g1p       = (uint*)alloc((size_t)N_NODES * 128);   // fp8 L1 acts 12.8MB; reused as g2p (3.2MB)
    // union region: buf (12.5MB, dead after build) -> a1 (bf16 25.6MB, born at agg1)
    void* uregion = alloc((size_t)N_NODES * 128 * 2);
    uint*  buf = (uint*)uregion;
    uint4* a1  = (uint4*)uregion;
    uchar_t* g2p = (uchar_t*)g1p;  // g1p dead after k_agg1; written by k_gemm2 after

    hipMemsetAsync(flag, 0, zero_bytes, stream);

    k_prep<<<80, 256, 0, stream>>>(W1, W2, wt1g, w2tg, ei, flag);
    k_bucket<<<(N_EDGES + CHUNK - 1) / CHUNK, 256, 0, stream>>>(ei, flag, cnt, buf);
    k_build<<<NB, 256, 0, stream>>>(buf, cnt, row_start, dinv, csr_src);
    k_gemm1<<<(N_NODES + 127) / 128, 256, 0, stream>>>((const float4*)x, (const uint4*)wt1g, dinv, g1p);
    k_agg1<<<N_NODES / 16, 256, 0, stream>>>((const uint2*)g1p, dinv, b1, row_start, csr_src, a1);
    k_gemm2<<<(N_NODES + 127) / 128, 256, 0, stream>>>((const uint4*)a1, (const uint4*)w2tg, dinv, g2p);
    k_agg2<<<N_NODES / 32, 256, 0, stream>>>((const uint*)g2p, dinv, b2, row_start, csr_src, (float4*)out);
}